// Round 15
// baseline (513.737 us; speedup 1.0000x reference)
//
#include <hip/hip_runtime.h>
#include <math.h>

#define EPS   1e-5f
#define NSEQ  197
#define DIM   384
#define NH    12
#define HD    32
#define MLPH  1536
#define NN2   38809          // 197*197
#define NROWS 6304           // 32*197
#define NPIX  1241888        // 32*38809
#define XSIZE 2420736        // 32*197*384 — exact size of output 0
#define SQF   0.4204482076268572f   // 32^(-0.25)

typedef __bf16 bf16;
typedef __attribute__((ext_vector_type(2))) __fp16 fp16x2;
typedef __attribute__((ext_vector_type(2))) float floatx2;
typedef __attribute__((ext_vector_type(8))) __bf16 bf16x8;
typedef __attribute__((ext_vector_type(4))) float floatx4;
typedef unsigned int u32;
typedef const __attribute__((address_space(1))) u32* gptr_t;
typedef __attribute__((address_space(3))) u32* lptr_t;

// ---- stats scratch layout (floats, inside ws) ----
#define ST_MOMSUM  0      // 12
#define ST_MOMPROD 16     // 144 (i<=j at i*12+j)
#define ST_SC1     160    // 36
#define ST_SH1     200    // 36
#define ST_S2      256    // 64*36
#define ST_SS2     2560   // 64*36
#define ST_SC2     4864   // 36
#define ST_SH2     4900   // 36
#define ST_P3      4992   // 64*36 (S3[12],S3q[12],S30[12] per slot)
#define ST_ABG     8832   // 36 (alpha,beta,gamma)
#define ST_TOTAL   8896

// ---- workspace offsets (float slots) ----
#define O_HB    0ull              // bf16 [6400][384]  (h, then outm, then h2)
#define O_Q     1228800ull        // bf16 [32*12][197][32] (q, SQF folded)
#define O_K     3649536ull        // bf16 (k, SQF folded)
#define O_V     6070272ull        // fp32 v
#define O_ATT0  8491008ull        // fp32 14902656 floats; m1 (bf16) aliases
#define O_X1    23393664ull       // fp32 2420736
#define O_WQKV  25814400ull       // bf16 1152x384
#define O_WPRJ  26035584ull       // bf16 384x384
#define O_WFC1  26109312ull       // bf16 1536x384
#define O_WFC2  26404224ull       // bf16 384x1536
#define O_STATS 26699136ull
#define WS_FLOATS (O_STATS + ST_TOTAL)          // ~107 MB — baseline requirement
// mid-ws tier: persisted dw output s as fp16 pairs (u32 [32*18][NN2], 89.4 MB)
#define O_SBUF  (O_STATS + ST_TOTAL)            // 26708032 (u32 slots == float slots)
#define SBUF_WORDS 22353984ull                  // 32*18*NN2
#define WS_FLOATS_MID (O_SBUF + SBUF_WORDS)     // 49062016 floats ≈ 196.2 MB

// ---- bf16x2 pack/unpack (fallback k_p3 path) ----
__device__ __forceinline__ u32 pack2(float a, float b) {
    u32 ua = __builtin_bit_cast(u32, a);
    u32 ub = __builtin_bit_cast(u32, b);
    return (ua >> 16) | (ub & 0xffff0000u);
}
__device__ __forceinline__ float unpk_lo(u32 w) { return __builtin_bit_cast(float, w << 16); }
__device__ __forceinline__ float unpk_hi(u32 w) { return __builtin_bit_cast(float, w & 0xffff0000u); }

// ---- fp16x2 pack/unpack ----
__device__ __forceinline__ u32 packh2(float a, float b) {
    fp16x2 h = __builtin_amdgcn_cvt_pkrtz(a, b);   // v_cvt_pkrtz_f16_f32
    return __builtin_bit_cast(u32, h);
}
__device__ __forceinline__ float unph_lo(u32 w) {
    fp16x2 h = __builtin_bit_cast(fp16x2, w);
    return (float)h.x;
}
__device__ __forceinline__ float unph_hi(u32 w) {
    fp16x2 h = __builtin_bit_cast(fp16x2, w);
    return (float)h.y;
}

// ---- DPP sum reduce (VALU pipe — no LDS-pipe ds_swizzle) ----
template <int CTRL>
__device__ __forceinline__ float dpp_addf(float v) {
    int x = __builtin_amdgcn_update_dpp(0, __builtin_bit_cast(int, v),
                                        CTRL, 0xF, 0xF, true);
    return v + __builtin_bit_cast(float, x);
}
__device__ __forceinline__ float red16(float v) {
    v = dpp_addf<0xB1>(v);    // quad_perm [1,0,3,2]  = xor 1
    v = dpp_addf<0x4E>(v);    // quad_perm [2,3,0,1]  = xor 2
    v = dpp_addf<0x141>(v);   // ROW_HALF_MIRROR      = pair across quads (8-group sum)
    v = dpp_addf<0x140>(v);   // ROW_MIRROR           = combine the two 8-groups (16-row sum)
    return v;
}

// ---- PACKED fp16-pair DPP reduce: one v_mov_dpp + v_pk_add_f16 per level
// reduces BOTH channels of a fp16x2 word at once (half the instructions).
template <int CTRL>
__device__ __forceinline__ u32 dpp_addh(u32 v) {
    int x = __builtin_amdgcn_update_dpp(0, __builtin_bit_cast(int, v),
                                        CTRL, 0xF, 0xF, true);
    fp16x2 a = __builtin_bit_cast(fp16x2, v);
    fp16x2 b = __builtin_bit_cast(fp16x2, (u32)x);
    fp16x2 c = a + b;                       // v_pk_add_f16
    return __builtin_bit_cast(u32, c);
}
__device__ __forceinline__ u32 red16h(u32 v) {
    v = dpp_addh<0xB1>(v);
    v = dpp_addh<0x4E>(v);
    v = dpp_addh<0x141>(v);
    v = dpp_addh<0x140>(v);
    return v;
}

// ============================ weight fp32 -> bf16 ========================
__global__ __launch_bounds__(256) void k_cvt(const float* __restrict__ s0,
                                             const float* __restrict__ s1,
                                             const float* __restrict__ s2,
                                             const float* __restrict__ s3,
                                             bf16* __restrict__ d0,
                                             bf16* __restrict__ d1,
                                             bf16* __restrict__ d2,
                                             bf16* __restrict__ d3) {
    const int w = blockIdx.y;
    const float* s = (w == 0) ? s0 : (w == 1) ? s1 : (w == 2) ? s2 : s3;
    bf16* d = (w == 0) ? d0 : (w == 1) ? d1 : (w == 2) ? d2 : d3;
    const int n = (w == 0) ? 442368 : (w == 1) ? 147456 : 589824;
    for (int i = blockIdx.x * 256 + threadIdx.x; i < n; i += gridDim.x * 256)
        d[i] = (bf16)s[i];
}

// ============================ LayerNorm (x*0.5) -> bf16 ==================
__global__ __launch_bounds__(384) void k_ln(const float* __restrict__ xin,
                                            const float* __restrict__ g,
                                            const float* __restrict__ bb,
                                            bf16* __restrict__ hout) {
    const int r = blockIdx.x;
    const int t = threadIdx.x;
    float v = xin[(size_t)r * DIM + t] * 0.5f;
    float s = v, sq = v * v;
#pragma unroll
    for (int off = 32; off >= 1; off >>= 1) {
        s  += __shfl_xor(s, off);
        sq += __shfl_xor(sq, off);
    }
    __shared__ float ls[6], lq[6];
    __shared__ float mv[2];
    const int wid = t >> 6;
    if ((t & 63) == 0) { ls[wid] = s; lq[wid] = sq; }
    __syncthreads();
    if (t == 0) {
        float S = 0.f, Q = 0.f;
        for (int i = 0; i < 6; ++i) { S += ls[i]; Q += lq[i]; }
        float m = S / (float)DIM;
        mv[0] = m;
        mv[1] = rsqrtf(Q / (float)DIM - m * m + EPS);
    }
    __syncthreads();
    hout[(size_t)r * DIM + t] = (bf16)((v - mv[0]) * mv[1] * g[t] + bb[t]);
}

// =============== 128x128 bf16 MFMA GEMM core: C = A[M][K] @ B[N][K]^T ====
template <int KDIM>
__device__ __forceinline__ void mgemm(const bf16* __restrict__ A,
                                      const bf16* __restrict__ B,
                                      int row0, int col0,
                                      floatx4 (&acc)[4][4]) {
    __shared__ bf16 As[128 * 32];
    __shared__ bf16 Bs[128 * 32];
    const int tid = threadIdx.x;
    const int lane = tid & 63, wave = tid >> 6;
    const int wy = wave >> 1, wx = wave & 1;
    const int quad = lane >> 4, l15 = lane & 15;
    for (int k0 = 0; k0 < KDIM; k0 += 32) {
#pragma unroll
        for (int i = 0; i < 2; ++i) {
            const int e = (i * 256 + tid) * 8;           // bf16 elem offset in tile
            const int r = e >> 5, kk = e & 31;
            __builtin_amdgcn_global_load_lds(
                (gptr_t)(A + (size_t)(row0 + r) * KDIM + k0 + kk),
                (lptr_t)(As + e), 16, 0, 0);
            __builtin_amdgcn_global_load_lds(
                (gptr_t)(B + (size_t)(col0 + r) * KDIM + k0 + kk),
                (lptr_t)(Bs + e), 16, 0, 0);
        }
        __syncthreads();
        bf16x8 af[4], bfr[4];
#pragma unroll
        for (int mi = 0; mi < 4; ++mi)
            af[mi] = *(const bf16x8*)&As[(wy * 64 + mi * 16 + l15) * 32 + quad * 8];
#pragma unroll
        for (int ni = 0; ni < 4; ++ni)
            bfr[ni] = *(const bf16x8*)&Bs[(wx * 64 + ni * 16 + l15) * 32 + quad * 8];
#pragma unroll
        for (int mi = 0; mi < 4; ++mi)
#pragma unroll
            for (int ni = 0; ni < 4; ++ni)
                acc[mi][ni] = __builtin_amdgcn_mfma_f32_16x16x32_bf16(
                    af[mi], bfr[ni], acc[mi][ni], 0, 0, 0);
        __syncthreads();
    }
}

// ============================ QKV GEMM + scatter =========================
// q,k stored as bf16 (SQF folded) — only k_score consumes them, via MFMA.
__global__ __launch_bounds__(256) void k_qkv(const bf16* __restrict__ h,
                                             const bf16* __restrict__ w,
                                             bf16* __restrict__ qb,
                                             bf16* __restrict__ kxb,
                                             float* __restrict__ v) {
    floatx4 acc[4][4] = {};
    const int row0 = blockIdx.y * 128, col0 = blockIdx.x * 128;
    mgemm<DIM>(h, w, row0, col0, acc);
    const int lane = threadIdx.x & 63, wave = threadIdx.x >> 6;
    const int wy = wave >> 1, wx = wave & 1;
    const int quad = lane >> 4, l15 = lane & 15;
#pragma unroll
    for (int mi = 0; mi < 4; ++mi)
#pragma unroll
        for (int reg = 0; reg < 4; ++reg) {
            int r = row0 + wy * 64 + mi * 16 + quad * 4 + reg;
            if (r >= NROWS) continue;
            int b = r / NSEQ, n = r - b * NSEQ;
#pragma unroll
            for (int ni = 0; ni < 4; ++ni) {
                int o = col0 + wx * 64 + ni * 16 + l15;
                int sec = o / DIM;
                int hh = (o >> 5) % NH;
                int dd = o & 31;
                float val = acc[mi][ni][reg];
                size_t idx = ((size_t)(b * NH + hh) * NSEQ + n) * HD + dd;
                if (sec == 2)      v[idx] = val;
                else if (sec == 0) qb[idx]  = (bf16)(val * SQF);
                else               kxb[idx] = (bf16)(val * SQF);
            }
        }
}

// ============================ proj GEMM + residual =======================
__global__ __launch_bounds__(256) void k_proj(const bf16* __restrict__ outm,
                                              const bf16* __restrict__ w,
                                              const float* __restrict__ pb,
                                              const float* __restrict__ x0,
                                              float* __restrict__ x1) {
    floatx4 acc[4][4] = {};
    const int row0 = blockIdx.y * 128, col0 = blockIdx.x * 128;
    mgemm<DIM>(outm, w, row0, col0, acc);
    const int lane = threadIdx.x & 63, wave = threadIdx.x >> 6;
    const int wy = wave >> 1, wx = wave & 1;
    const int quad = lane >> 4, l15 = lane & 15;
#pragma unroll
    for (int mi = 0; mi < 4; ++mi)
#pragma unroll
        for (int reg = 0; reg < 4; ++reg) {
            int r = row0 + wy * 64 + mi * 16 + quad * 4 + reg;
            if (r >= NROWS) continue;
#pragma unroll
            for (int ni = 0; ni < 4; ++ni) {
                int o = col0 + wx * 64 + ni * 16 + l15;
                x1[(size_t)r * DIM + o] =
                    x0[(size_t)r * DIM + o] + 2.f * (acc[mi][ni][reg] + pb[o]);
            }
        }
}

// ============================ fc1 GEMM + exact GELU -> bf16 ==============
__global__ __launch_bounds__(256) void k_fc1(const bf16* __restrict__ h,
                                             const bf16* __restrict__ w,
                                             const float* __restrict__ fb,
                                             bf16* __restrict__ m1) {
    floatx4 acc[4][4] = {};
    const int row0 = blockIdx.y * 128, col0 = blockIdx.x * 128;
    mgemm<DIM>(h, w, row0, col0, acc);
    const int lane = threadIdx.x & 63, wave = threadIdx.x >> 6;
    const int wy = wave >> 1, wx = wave & 1;
    const int quad = lane >> 4, l15 = lane & 15;
#pragma unroll
    for (int mi = 0; mi < 4; ++mi)
#pragma unroll
        for (int reg = 0; reg < 4; ++reg) {
            int r = row0 + wy * 64 + mi * 16 + quad * 4 + reg;
            if (r >= NROWS) continue;
#pragma unroll
            for (int ni = 0; ni < 4; ++ni) {
                int o = col0 + wx * 64 + ni * 16 + l15;
                float z = acc[mi][ni][reg] + fb[o];
                m1[(size_t)r * MLPH + o] =
                    (bf16)(0.5f * z * (1.f + erff(z * 0.70710678118654752f)));
            }
        }
}

// ============================ fc2 GEMM + scale + residual ================
__global__ __launch_bounds__(256) void k_fc2(const bf16* __restrict__ m1,
                                             const bf16* __restrict__ w,
                                             const float* __restrict__ fb,
                                             const float* __restrict__ scch,
                                             const float* __restrict__ x1,
                                             float* __restrict__ xout) {
    floatx4 acc[4][4] = {};
    const int row0 = blockIdx.y * 128, col0 = blockIdx.x * 128;
    mgemm<MLPH>(m1, w, row0, col0, acc);
    const int lane = threadIdx.x & 63, wave = threadIdx.x >> 6;
    const int wy = wave >> 1, wx = wave & 1;
    const int quad = lane >> 4, l15 = lane & 15;
#pragma unroll
    for (int mi = 0; mi < 4; ++mi)
#pragma unroll
        for (int reg = 0; reg < 4; ++reg) {
            int r = row0 + wy * 64 + mi * 16 + quad * 4 + reg;
            if (r >= NROWS) continue;
#pragma unroll
            for (int ni = 0; ni < 4; ++ni) {
                int o = col0 + wx * 64 + ni * 16 + l15;
                xout[(size_t)r * DIM + o] =
                    x1[(size_t)r * DIM + o] + 2.f * (acc[mi][ni][reg] + fb[o]) * scch[o];
            }
        }
}

// ==================== scores via MFMA + softmax ==========================
__global__ __launch_bounds__(256) void k_score(const bf16* __restrict__ qb,
                                               const bf16* __restrict__ kmat,
                                               float* __restrict__ att) {
    __shared__ bf16 Ks[208 * 32];     // 13312 B, zero-padded rows 197..207
    __shared__ bf16 Qs[16 * 32];      // 1024 B
    __shared__ float Ss[16][208];     // 13312 B
    const int bh = blockIdx.y;
    const int y0 = blockIdx.x * 16;
    const int tid = threadIdx.x;
    const size_t kb = (size_t)bh * (NSEQ * HD);
    {
        const u32* ksrc = (const u32*)(kmat + kb);
        u32* kdst = (u32*)Ks;
        for (int i = tid; i < 208 * 16; i += 256)
            kdst[i] = (i < NSEQ * 16) ? ksrc[i] : 0u;
        const u32* qsrc = (const u32*)(qb + kb);
        u32* qdst = (u32*)Qs;
        for (int i = tid; i < 16 * 16; i += 256) {
            int rr = i >> 4, yy = y0 + rr;
            qdst[i] = (yy < NSEQ) ? qsrc[(size_t)yy * 16 + (i & 15)] : 0u;
        }
    }
    __syncthreads();
    {
        const int lane = tid & 63;
        const int wave = tid >> 6;
        const int l15 = lane & 15, quad = lane >> 4;
        bf16x8 af = *(const bf16x8*)&Qs[l15 * 32 + quad * 8];
        for (int t = wave; t < 13; t += 4) {
            bf16x8 bfr = *(const bf16x8*)&Ks[(t * 16 + l15) * 32 + quad * 8];
            floatx4 c = {0.f, 0.f, 0.f, 0.f};
            c = __builtin_amdgcn_mfma_f32_16x16x32_bf16(af, bfr, c, 0, 0, 0);
#pragma unroll
            for (int reg = 0; reg < 4; ++reg)
                Ss[quad * 4 + reg][t * 16 + l15] = c[reg];
        }
    }
    __syncthreads();
    const int tx = tid & 15, ty = tid >> 4;
    const int y = y0 + ty;
    if (y >= NSEQ) return;
    float sc[13];
    float mx = -1e30f;
#pragma unroll
    for (int m = 0; m < 13; ++m) {
        int x = tx + m * 16;
        float d = (x < NSEQ) ? Ss[ty][x] : -1e30f;
        sc[m] = d;
        mx = fmaxf(mx, d);
    }
#pragma unroll
    for (int off = 8; off >= 1; off >>= 1) mx = fmaxf(mx, __shfl_xor(mx, off, 16));
    float ssum = 0.f;
#pragma unroll
    for (int m = 0; m < 13; ++m) {
        int x = tx + m * 16;
        float e = (x < NSEQ) ? __expf(sc[m] - mx) : 0.f;
        sc[m] = e;
        ssum += e;
    }
#pragma unroll
    for (int off = 8; off >= 1; off >>= 1) ssum += __shfl_xor(ssum, off, 16);
    const float rinv = 1.f / ssum;
    const size_t ab = (size_t)bh * NN2 + (size_t)y * NSEQ;
#pragma unroll
    for (int m = 0; m < 13; ++m) {
        int x = tx + m * 16;
        if (x < NSEQ) att[ab + x] = sc[m] * rinv;
    }
}

// ============================ channel moments of attn0 ===================
__global__ __launch_bounds__(256) void k_moments(const float* __restrict__ att,
                                                 float* __restrict__ stats) {
    float mu[12] = {};
    float pr[78] = {};
    const int stride = gridDim.x * 256;
    for (int p = blockIdx.x * 256 + threadIdx.x; p < NPIX; p += stride) {
        int b = p / NN2;
        int s = p - b * NN2;
        const float* base = att + (size_t)b * 12 * NN2 + s;
        float v[12];
#pragma unroll
        for (int i = 0; i < 12; ++i) v[i] = base[(size_t)i * NN2];
#pragma unroll
        for (int i = 0; i < 12; ++i) mu[i] += v[i];
#pragma unroll
        for (int i = 0; i < 12; ++i)
#pragma unroll
            for (int j = i; j < 12; ++j)
                pr[i * (23 - i) / 2 + j] += v[i] * v[j];
    }
#pragma unroll
    for (int s = 0; s < 12; ++s)
#pragma unroll
        for (int off = 32; off >= 1; off >>= 1) mu[s] += __shfl_xor(mu[s], off);
#pragma unroll
    for (int s = 0; s < 78; ++s)
#pragma unroll
        for (int off = 32; off >= 1; off >>= 1) pr[s] += __shfl_xor(pr[s], off);
    __shared__ float red[4][90];
    const int lane = threadIdx.x & 63, wid = threadIdx.x >> 6;
    if (lane == 0) {
#pragma unroll
        for (int s = 0; s < 12; ++s) red[wid][s] = mu[s];
#pragma unroll
        for (int s = 0; s < 78; ++s) red[wid][12 + s] = pr[s];
    }
    __syncthreads();
    const int t = threadIdx.x;
    if (t < 90) {
        float tot = red[0][t] + red[1][t] + red[2][t] + red[3][t];
        int addr;
        if (t < 12) addr = ST_MOMSUM + t;
        else {
            int tt = t - 12;
            int i = 0;
            while (tt >= 12 - i) { tt -= 12 - i; ++i; }
            addr = ST_MOMPROD + i * 12 + (i + tt);
        }
        atomicAdd(&stats[addr], tot);
    }
}

// ============================ finalize bn1 (analytic) ====================
__global__ __launch_bounds__(64) void k_fin1(const float* __restrict__ wexp,
                                             const float* __restrict__ g1,
                                             const float* __restrict__ b1,
                                             float* __restrict__ stats) {
    int o = threadIdx.x;
    if (o >= 36) return;
    const float invM = 1.f / (float)NPIX;
    float mu[12];
#pragma unroll
    for (int i = 0; i < 12; ++i) mu[i] = stats[ST_MOMSUM + i] * invM;
    float mean = 0.f;
#pragma unroll
    for (int i = 0; i < 12; ++i) mean += wexp[o * 12 + i] * mu[i];
    float e2 = 0.f;
    for (int i = 0; i < 12; ++i)
        for (int j = 0; j < 12; ++j) {
            int a = i < j ? i : j, bj = i < j ? j : i;
            e2 += wexp[o * 12 + i] * wexp[o * 12 + j] * stats[ST_MOMPROD + a * 12 + bj] * invM;
        }
    float var = e2 - mean * mean;
    float sc = g1[o] * rsqrtf(var + EPS);
    stats[ST_SC1 + o] = sc;
    stats[ST_SH1 + o] = b1[o] - mean * sc;
}

// ====== PASS A: expand (packed f32) + bn1 + relu6 -> fp16-packed b1, =====
// ====== dw conv in v_pk_fma_f16; stats via PACKED fp16 DPP reduce    =====
// (red16h: one v_mov_dpp + v_pk_add_f16 per level reduces both channels
//  at once — halves the former 4x red16 f32 instruction count.)
template <int STORE>
__global__ __launch_bounds__(256) void k_sums2(const float* __restrict__ att,
                                               const float* __restrict__ wexp,
                                               const float* __restrict__ dww,
                                               const float* __restrict__ stats,
                                               float* __restrict__ statw,
                                               u32* __restrict__ sbuf) {
    __shared__ u32  b1p[18][256];
    __shared__ floatx2 wexp2[216];   // [pp*12+i] = (wexp[2pp][i], wexp[2pp+1][i])
    __shared__ fp16x2 dw2h[162];     // [pp*9+t]  = f16 (dww[2pp][t], dww[2pp+1][t])
    __shared__ floatx2 sc1p[18], sh1p[18];
    __shared__ float red[16][73];    // [leader][72 partials]
    const int b = blockIdx.z;
    const int oy0 = blockIdx.y * 14, ox0 = blockIdx.x * 14;
    const int tid = threadIdx.x;
    for (int i = tid; i < 216; i += 256) {
        int pp = i / 12, ii = i - pp * 12;
        floatx2 t = {wexp[(2 * pp) * 12 + ii], wexp[(2 * pp + 1) * 12 + ii]};
        wexp2[i] = t;
    }
    for (int i = tid; i < 162; i += 256) {
        int pp = i / 9, t9 = i - pp * 9;
        fp16x2 t = {(__fp16)dww[(2 * pp) * 9 + t9], (__fp16)dww[(2 * pp + 1) * 9 + t9]};
        dw2h[i] = t;
    }
    if (tid < 18) {
        floatx2 a = {stats[ST_SC1 + 2 * tid], stats[ST_SC1 + 2 * tid + 1]};
        floatx2 bshift = {stats[ST_SH1 + 2 * tid], stats[ST_SH1 + 2 * tid + 1]};
        sc1p[tid] = a;
        sh1p[tid] = bshift;
    }
    const int lx = tid & 15, ly = tid >> 4;
    const int gy = oy0 - 1 + ly, gx = ox0 - 1 + lx;
    const bool valid = (gy >= 0 && gy < NSEQ && gx >= 0 && gx < NSEQ);
    float a0v[12];
#pragma unroll
    for (int i = 0; i < 12; ++i)
        a0v[i] = valid ? att[(size_t)(b * 12 + i) * NN2 + (size_t)gy * NSEQ + gx] : 0.f;
    __syncthreads();
    const floatx2 vzero = {0.f, 0.f};
    const floatx2 vsix  = {6.f, 6.f};
#pragma unroll 3
    for (int pp = 0; pp < 18; ++pp) {
        floatx2 t = vzero;
#pragma unroll
        for (int i = 0; i < 12; ++i) {
            floatx2 av = {a0v[i], a0v[i]};
            t = __builtin_elementwise_fma(wexp2[pp * 12 + i], av, t);
        }
        t = __builtin_elementwise_fma(sc1p[pp], t, sh1p[pp]);
        t = __builtin_elementwise_max(t, vzero);
        t = __builtin_elementwise_min(t, vsix);
        if (!valid) t = vzero;
        b1p[pp][tid] = packh2(t.x, t.y);   // fp16 pairs
    }
    __syncthreads();
    const bool inter = (ly >= 1 && ly <= 14 && lx >= 1 && lx <= 14 &&
                        gy < NSEQ && gx < NSEQ);
    const int base = inter ? ((ly - 1) * 16 + (lx - 1)) : 0;
    const int leader = tid >> 4;
    const size_t pix = (size_t)gy * NSEQ + gx;
    const fp16x2 hzero = {(__fp16)0.f, (__fp16)0.f};
#pragma unroll 3
    for (int pp = 0; pp < 18; ++pp) {
        fp16x2 sh = hzero;
        if (inter) {
            const u32* bp = &b1p[pp][base];
#pragma unroll
            for (int dy = 0; dy < 3; ++dy)
#pragma unroll
                for (int dx = 0; dx < 3; ++dx) {
                    fp16x2 bv = __builtin_bit_cast(fp16x2, bp[dy * 16 + dx]);
                    sh = __builtin_elementwise_fma(dw2h[pp * 9 + dy * 3 + dx], bv, sh);
                }
            if (STORE)
                sbuf[((size_t)(b * 18 + pp)) * NN2 + pix] = __builtin_bit_cast(u32, sh);
        }
        fp16x2 sq = sh * sh;                              // v_pk_mul_f16
        u32 rs = red16h(__builtin_bit_cast(u32, sh));     // packed pair reduce
        u32 rq = red16h(__builtin_bit_cast(u32, sq));
        if ((tid & 15) == 0) {
            red[leader][pp * 4 + 0] = unph_lo(rs);
            red[leader][pp * 4 + 1] = unph_hi(rs);
            red[leader][pp * 4 + 2] = unph_lo(rq);
            red[leader][pp * 4 + 3] = unph_hi(rq);
        }
    }
    __syncthreads();
    if (tid < 72) {
        float tot = 0.f;
        for (int l = 0; l < 16; ++l) tot += red[l][tid];
        int pp = tid >> 2, j = tid & 3;
        int c = 2 * pp + (j & 1);
        int isq = j >> 1;
        int slot = (blockIdx.z * 225 + blockIdx.y * 15 + blockIdx.x) & 63;
        atomicAdd(&statw[(isq ? ST_SS2 : ST_S2) + slot * 36 + c], tot);
    }
}

__global__ __launch_bounds__(64) void k_fin2(const float* __restrict__ g2,
                                             const float* __restrict__ b2,
                                             float* __restrict__ stats) {
    int o = threadIdx.x;
    if (o >= 36) return;
    float S = 0.f, SS = 0.f;
    for (int sl = 0; sl < 64; ++sl) {
        S += stats[ST_S2 + sl * 36 + o];
        SS += stats[ST_SS2 + sl * 36 + o];
    }
    const float invM = 1.f / (float)NPIX;
    float m = S * invM, var = SS * invM - m * m;
    float sc = g2[o] * rsqrtf(var + EPS);
    stats[ST_SC2 + o] = sc;
    stats[ST_SH2 + o] = b2[o] - m * sc;
}

// ====== PASS B (thin, mid-ws): read persisted fp16 s, bn2+relu6+project ==
__global__ __launch_bounds__(256) void k_p3f(const float* __restrict__ att,
                                             const u32* __restrict__ sbuf,
                                             const float* __restrict__ pw,
                                             const float* __restrict__ stats,
                                             float* __restrict__ datt,
                                             float* __restrict__ statw) {
    __shared__ floatx2 pw2[216];     // [k*36+ch] = (pw[2k][ch], pw[2k+1][ch]), k=c-pair
    __shared__ floatx2 sc2p[18], sh2p[18];
    __shared__ float red2[16][37];
    const int tid = threadIdx.x;
    for (int i = tid; i < 216; i += 256) {
        int k = i / 36, ch = i - k * 36;
        floatx2 t = {pw[(2 * k) * 36 + ch], pw[(2 * k + 1) * 36 + ch]};
        pw2[i] = t;
    }
    if (tid < 18) {
        floatx2 a = {stats[ST_SC2 + 2 * tid], stats[ST_SC2 + 2 * tid + 1]};
        floatx2 bshift = {stats[ST_SH2 + 2 * tid], stats[ST_SH2 + 2 * tid + 1]};
        sc2p[tid] = a;
        sh2p[tid] = bshift;
    }
    __syncthreads();
    const int p = blockIdx.x * 256 + tid;
    const bool act = p < NPIX;
    int b = 0, s = 0;
    if (act) { b = p / NN2; s = p - b * NN2; }
    const floatx2 vzero = {0.f, 0.f};
    const floatx2 vsix  = {6.f, 6.f};
    floatx2 a3p[6] = {vzero, vzero, vzero, vzero, vzero, vzero};
    float a0v[12] = {};
    if (act) {
        const u32* sb = sbuf + (size_t)b * 18 * NN2 + s;
#pragma unroll 3
        for (int pp = 0; pp < 18; ++pp) {
            u32 w = sb[(size_t)pp * NN2];
            floatx2 sv = {unph_lo(w), unph_hi(w)};
            floatx2 u = __builtin_elementwise_fma(sc2p[pp], sv, sh2p[pp]);
            u = __builtin_elementwise_max(u, vzero);
            u = __builtin_elementwise_min(u, vsix);
            floatx2 ux = {u.x, u.x};
            floatx2 uy = {u.y, u.y};
#pragma unroll
            for (int k = 0; k < 6; ++k) {
                a3p[k] = __builtin_elementwise_fma(pw2[k * 36 + 2 * pp], ux, a3p[k]);
                a3p[k] = __builtin_elementwise_fma(pw2[k * 36 + 2 * pp + 1], uy, a3p[k]);
            }
        }
        const float* ab = att + (size_t)b * 12 * NN2 + s;
#pragma unroll
        for (int c = 0; c < 12; ++c) a0v[c] = ab[(size_t)c * NN2];
#pragma unroll
        for (int k = 0; k < 6; ++k) {
            datt[(size_t)(b * 12 + 2 * k) * NN2 + s]     = a3p[k].x;
            datt[(size_t)(b * 12 + 2 * k + 1) * NN2 + s] = a3p[k].y;
        }
    }
    const int leader = tid >> 4;
#pragma unroll
    for (int k = 0; k < 6; ++k) {
        float v0 = a3p[k].x, v1 = a3p[k].y;
        float r30 = red16(v0);
        float r31 = red16(v1);
        float rq0 = red16(v0 * v0);
        float rq1 = red16(v1 * v1);
        float rx0 = red16(v0 * a0v[2 * k]);
        float rx1 = red16(v1 * a0v[2 * k + 1]);
        if ((tid & 15) == 0) {
            red2[leader][2 * k]          = r30;
            red2[leader][2 * k + 1]      = r31;
            red2[leader][12 + 2 * k]     = rq0;
            red2[leader][12 + 2 * k + 1] = rq1;
            red2[leader][24 + 2 * k]     = rx0;
            red2[leader][24 + 2 * k + 1] = rx1;
        }
    }
    __syncthreads();
    if (tid < 36) {
        float tot = 0.f;
        for (int l = 0; l < 16; ++l) tot += red2[l][tid];
        int slot = blockIdx.x & 63;
        atomicAdd(&statw[ST_P3 + slot * 36 + tid], tot);
    }
}

// ====== PASS B (fallback, small-ws): full recompute + fused stats =======
__global__ __launch_bounds__(256) void k_p3(const float* __restrict__ att,
                                            const float* __restrict__ wexp,
                                            const float* __restrict__ dww,
                                            const float* __restrict__ pw,
                                            const float* __restrict__ stats,
                                            float* __restrict__ datt,
                                            float* __restrict__ statw) {
    __shared__ u32  b1p[18][256];
    __shared__ float wexps[432];
    __shared__ float dws[324];
    __shared__ float pws[432];
    __shared__ float sc1s[36], sh1s[36], sc2s[36], sh2s[36];
    __shared__ float red2[32][37];
    const int b = blockIdx.z;
    const int oy0 = blockIdx.y * 14, ox0 = blockIdx.x * 14;
    const int tid = threadIdx.x;
    for (int i = tid; i < 432; i += 256) { wexps[i] = wexp[i]; pws[i] = pw[i]; }
    for (int i = tid; i < 324; i += 256) dws[i] = dww[i];
    if (tid < 36) {
        sc1s[tid] = stats[ST_SC1 + tid]; sh1s[tid] = stats[ST_SH1 + tid];
        sc2s[tid] = stats[ST_SC2 + tid]; sh2s[tid] = stats[ST_SH2 + tid];
    }
    const int lx = tid & 15, ly = tid >> 4;
    const int gy = oy0 - 1 + ly, gx = ox0 - 1 + lx;
    const bool valid = (gy >= 0 && gy < NSEQ && gx >= 0 && gx < NSEQ);
    float a0v[12];
#pragma unroll
    for (int i = 0; i < 12; ++i)
        a0v[i] = valid ? att[(size_t)(b * 12 + i) * NN2 + (size_t)gy * NSEQ + gx] : 0.f;
    __syncthreads();
#pragma unroll 3
    for (int pp = 0; pp < 18; ++pp) {
        float t0 = 0.f, t1 = 0.f;
#pragma unroll
        for (int i = 0; i < 12; ++i) {
            t0 = fmaf(wexps[(2 * pp) * 12 + i], a0v[i], t0);
            t1 = fmaf(wexps[(2 * pp + 1) * 12 + i], a0v[i], t1);
        }
        t0 = fminf(fmaxf(fmaf(sc1s[2 * pp], t0, sh1s[2 * pp]), 0.f), 6.f);
        t1 = fminf(fmaxf(fmaf(sc1s[2 * pp + 1], t1, sh1s[2 * pp + 1]), 0.f), 6.f);
        if (!valid) { t0 = 0.f; t1 = 0.f; }
        b1p[pp][tid] = pack2(t0, t1);
    }
    __syncthreads();
    const bool inter = (ly >= 1 && ly <= 14 && lx >= 1 && lx <= 14 &&
                        gy < NSEQ && gx < NSEQ);
    float a3v[12] = {};
    if (inter) {
        const int base = (ly - 1) * 16 + (lx - 1);
#pragma unroll 3
        for (int pp = 0; pp < 18; ++pp) {
            const u32* bp = &b1p[pp][base];
            float s0 = 0.f, s1 = 0.f;
#pragma unroll
            for (int dy = 0; dy < 3; ++dy)
#pragma unroll
                for (int dx = 0; dx < 3; ++dx) {
                    u32 w = bp[dy * 16 + dx];
                    s0 = fmaf(dws[(2 * pp) * 9 + dy * 3 + dx], unpk_lo(w), s0);
                    s1 = fmaf(dws[(2 * pp + 1) * 9 + dy * 3 + dx], unpk_hi(w), s1);
                }
            float u0 = fminf(fmaxf(fmaf(sc2s[2 * pp], s0, sh2s[2 * pp]), 0.f), 6.f);
            float u1 = fminf(fmaxf(fmaf(sc2s[2 * pp + 1], s1, sh2s[2 * pp + 1]), 0.f), 6.f);
#pragma unroll
            for (int c = 0; c < 12; ++c)
                a3v[c] = fmaf(pws[c * 36 + 2 * pp], u0,
                         fmaf(pws[c * 36 + 2 * pp + 1], u1, a3v[c]));
        }
        const size_t pix = (size_t)gy * NSEQ + gx;
#pragma unroll
        for (int c = 0; c < 12; ++c)
            datt[(size_t)(b * 12 + c) * NN2 + pix] = a3v[c];
    }
    const int leader = tid >> 3;
#pragma unroll
    for (int c = 0; c < 12; ++c) {
        float r3  = red16(a3v[c]);
        float rq  = red16(a3v[c] * a3v[c]);
        float r30 = red16(a3v[c] * a0v[c]);
        if ((tid & 7) == 0) {
            red2[leader][c]      = r3;
            red2[leader][12 + c] = rq;
            red2[leader][24 + c] = r30;
        }
    }
    __syncthreads();
    if (tid < 36) {
        float tot = 0.f;
        for (int l = 0; l < 32; l += 2) tot += red2[l][tid];
        int slot = (blockIdx.z * 225 + blockIdx.y * 15 + blockIdx.x) & 63;
        atomicAdd(&statw[ST_P3 + slot * 36 + tid], tot);
    }
}

// ============ finalize bn3 + adapt_bn -> affine alpha/beta/gamma =========
__global__ __launch_bounds__(64) void k_fin3(const float* __restrict__ g3,
                                             const float* __restrict__ b3,
                                             const float* __restrict__ ag,
                                             const float* __restrict__ ab,
                                             float* __restrict__ stats) {
    int c = threadIdx.x;
    if (c >= 12) return;
    float S3 = 0.f, S3q = 0.f, S30 = 0.f;
    for (int sl = 0; sl < 64; ++sl) {
        const float* p = stats + ST_P3 + sl * 36;
        S3 += p[c]; S3q += p[12 + c]; S30 += p[24 + c];
    }
    float S0  = stats[ST_MOMSUM + c];
    float S0q = stats[ST_MOMPROD + c * 12 + c];
    const float M = (float)NPIX;
    float m3 = S3 / M, v3 = S3q / M - m3 * m3;
    float pp = g3[c] * rsqrtf(v3 + EPS);
    float qq = b3[c] - m3 * pp;
    float my = (pp * S3 + S0) / M + qq;
    float Syq = pp * pp * S3q + S0q + qq * qq * M + 2.f * pp * S30 + 2.f * pp * qq * S3 + 2.f * qq * S0;
    float vy = Syq / M - my * my;
    float rr = ag[c] * rsqrtf(vy + EPS);
    float ss = ab[c] - my * rr;
    stats[ST_ABG + c] = rr * pp;
    stats[ST_ABG + 12 + c] = rr;
    stats[ST_ABG + 24 + c] = rr * qq + ss;
}

// ====== final attn (in-place affine) + AV via MFMA -> bf16 outm ==========
__global__ __launch_bounds__(256) void k_p4(float* __restrict__ datt,
                                            const float* __restrict__ att0,
                                            const float* __restrict__ v,
                                            const float* __restrict__ stats,
                                            bf16* __restrict__ outm) {
    __shared__ bf16 Vtb[32 * 224];    // V^T: [d][x], zero-padded x>=197
    __shared__ bf16 As[16 * 224];     // av rows (bf16), zero-padded
    const int bh = blockIdx.y;
    const int b = bh / 12, hh = bh - b * 12;
    const int y0 = blockIdx.x * 16;
    const int tid = threadIdx.x;
    const size_t vb = (size_t)bh * (NSEQ * HD);
    for (int i = tid; i < 32 * 224; i += 256) {
        int x = i >> 5, d = i & 31;
        float val = (x < NSEQ) ? v[vb + (size_t)x * HD + d] : 0.f;
        Vtb[d * 224 + x] = (bf16)val;
    }
    const float alpha = stats[ST_ABG + hh];
    const float beta  = stats[ST_ABG + 12 + hh];
    const float gamma = stats[ST_ABG + 24 + hh];
    const int tx = tid & 15, ty = tid >> 4;
    const int y = y0 + ty;
    const size_t ab = (size_t)bh * NN2 + (size_t)y * NSEQ;
    As[ty * 224 + 208 + tx] = (bf16)0.f;      // pad cols 208..223
#pragma unroll
    for (int m = 0; m < 13; ++m) {
        int x = tx + m * 16;
        float av = 0.f;
        if (y < NSEQ && x < NSEQ) {
            av = alpha * datt[ab + x] + beta * att0[ab + x] + gamma;
            datt[ab + x] = av;
        }
        As[ty * 224 + x] = (bf16)av;
    }
    __syncthreads();
    const int lane = tid & 63, wave = tid >> 6;
    if (wave < 2) {
        const int l15 = lane & 15, quad = lane >> 4;
        floatx4 c = {0.f, 0.f, 0.f, 0.f};
#pragma unroll
        for (int ks = 0; ks < 7; ++ks) {
            bf16x8 af  = *(const bf16x8*)&As[l15 * 224 + ks * 32 + quad * 8];
            bf16x8 bfr = *(const bf16x8*)&Vtb[(wave * 16 + l15) * 224 + ks * 32 + quad * 8];
            c = __builtin_amdgcn_mfma_f32_16x16x32_bf16(af, bfr, c, 0, 0, 0);
        }
#pragma unroll
        for (int reg = 0; reg < 4; ++reg) {
            int yy = y0 + quad * 4 + reg;
            if (yy < NSEQ)
                outm[((size_t)b * NSEQ + yy) * DIM + hh * HD + wave * 16 + l15] =
                    (bf16)c[reg];
        }
    }
}

// ========================================================================
extern "C" void kernel_launch(void* const* d_in, const int* in_sizes, int n_in,
                              void* d_out, int out_size, void* d_ws, size_t ws_size,
                              hipStream_t stream) {
    const float* x     = (const float*)d_in[0];
    const float* ln1g  = (const float*)d_in[1];
    const float* ln1b  = (const float*)d_in[2];
    const float* qkvw  = (const float*)d_in[3];
    const float* wexp  = (const float*)d_in[4];
    const float* bn1g  = (const float*)d_in[5];
    const float* bn1b  = (const float*)d_in[6];
    const float* dww   = (const float*)d_in[7];
    const float* bn2g  = (const float*)d_in[8];
    const float* bn2b  = (const float*)d_in[9];
    const float* prow  = (const float*)d_in[10];
    const float* bn3g  = (const float*)d_in[11];
    const float* bn3b  = (const float*)d_in[12];
    const float* abng  = (const float*)d_in[13];
    const float* abnb  = (const float*)d_in[14];
    const float* projw = (const float*)d_in[15];
    const float* projb = (const float*)d_in[16];
    const float* ln2g  = (const float*)d_in[17];
    const float* ln2b  = (const float*)d_in[18];
    const float* fc1w  = (const float*)d_in[19];
    const float* fc1b  = (const float*)d_in[20];
    const float* fc2w  = (const float*)d_in[21];
    const float* fc2b  = (const float*)d_in[22];
    const float* scch  = (const float*)d_in[23];

    if (ws_size < WS_FLOATS * sizeof(float)) return;   // base requirement ~107 MB
    const bool mid = ws_size >= WS_FLOATS_MID * sizeof(float);  // ~196 MB tier

    float* W     = (float*)d_ws;
    bf16*  hb    = (bf16*)(W + O_HB);     // h, then outm, then h2 (sequential)
    bf16*  qbv   = (bf16*)(W + O_Q);      // bf16 q (SQF folded)
    bf16*  kxb   = (bf16*)(W + O_K);      // bf16 k (SQF folded)
    float* v     = W + O_V;
    float* att0  = W + O_ATT0;
    float* x1    = W + O_X1;
    bf16*  m1    = (bf16*)(W + O_ATT0);   // alias: att0 dead after k_p4
    bf16*  wqkvb = (bf16*)(W + O_WQKV);
    bf16*  wprjb = (bf16*)(W + O_WPRJ);
    bf16*  wfc1b = (bf16*)(W + O_WFC1);
    bf16*  wfc2b = (bf16*)(W + O_WFC2);
    float* stats = W + O_STATS;
    u32*   sbuf  = (u32*)(W + O_SBUF);    // only valid if mid

    float* xout = (float*)d_out;
    float* datt = xout + XSIZE;

    (void)hipMemsetAsync(stats, 0, ST_TOTAL * sizeof(float), stream);
    k_cvt<<<dim3(288, 4), 256, 0, stream>>>(qkvw, projw, fc1w, fc2w,
                                            wqkvb, wprjb, wfc1b, wfc2b);
    k_ln<<<NROWS, 384, 0, stream>>>(x, ln1g, ln1b, hb);
    k_qkv<<<dim3(9, 50), 256, 0, stream>>>(hb, wqkvb, qbv, kxb, v);
    k_score<<<dim3(13, 384), 256, 0, stream>>>(qbv, kxb, att0);
    k_moments<<<512, 256, 0, stream>>>(att0, stats);
    k_fin1<<<1, 64, 0, stream>>>(wexp, bn1g, bn1b, stats);
    if (mid) {
        k_sums2<1><<<dim3(15, 15, 32), 256, 0, stream>>>(att0, wexp, dww, stats, stats, sbuf);
        k_fin2<<<1, 64, 0, stream>>>(bn2g, bn2b, stats);
        k_p3f<<<(NPIX + 255) / 256, 256, 0, stream>>>(att0, sbuf, prow, stats, datt, stats);
    } else {
        k_sums2<0><<<dim3(15, 15, 32), 256, 0, stream>>>(att0, wexp, dww, stats, stats, nullptr);
        k_fin2<<<1, 64, 0, stream>>>(bn2g, bn2b, stats);
        k_p3<<<dim3(15, 15, 32), 256, 0, stream>>>(att0, wexp, dww, prow, stats, datt, stats);
    }
    k_fin3<<<1, 64, 0, stream>>>(bn3g, bn3b, abng, abnb, stats);
    k_p4<<<dim3(13, 384), 256, 0, stream>>>(datt, att0, v, stats, hb);
    k_proj<<<dim3(3, 50), 256, 0, stream>>>(hb, wprjb, projb, x, x1);
    k_ln<<<NROWS, 384, 0, stream>>>(x1, ln2g, ln2b, hb);
    k_fc1<<<dim3(12, 50), 256, 0, stream>>>(hb, wfc1b, fc1b, m1);
    k_fc2<<<dim3(3, 50), 256, 0, stream>>>(m1, wfc2b, fc2b, scch, x1, xout);
}

// Round 17
// 498.772 us; speedup vs baseline: 1.0300x; 1.0300x over previous
//
#include <hip/hip_runtime.h>
#include <math.h>

#define EPS   1e-5f
#define NSEQ  197
#define DIM   384
#define NH    12
#define HD    32
#define MLPH  1536
#define NN2   38809          // 197*197
#define NROWS 6304           // 32*197
#define NPIX  1241888        // 32*38809
#define XSIZE 2420736        // 32*197*384 — exact size of output 0
#define SQF   0.4204482076268572f   // 32^(-0.25)

typedef __bf16 bf16;
typedef __attribute__((ext_vector_type(2))) __fp16 fp16x2;
typedef __attribute__((ext_vector_type(2))) float floatx2;
typedef __attribute__((ext_vector_type(8))) __bf16 bf16x8;
typedef __attribute__((ext_vector_type(4))) float floatx4;
typedef unsigned int u32;
typedef const __attribute__((address_space(1))) u32* gptr_t;
typedef __attribute__((address_space(3))) u32* lptr_t;

// ---- stats scratch layout (floats, inside ws) ----
#define ST_MOMSUM  0      // 12
#define ST_MOMPROD 16     // 144 (i<=j at i*12+j)
#define ST_SC1     160    // 36
#define ST_SH1     200    // 36
#define ST_S2      256    // 64*36
#define ST_SS2     2560   // 64*36
#define ST_SC2     4864   // 36
#define ST_SH2     4900   // 36
#define ST_P3      4992   // 64*36 (S3[12],S3q[12],S30[12] per slot)
#define ST_ABG     8832   // 36 (alpha,beta,gamma)
#define ST_TOTAL   8896

// ---- workspace offsets (float slots) ----
// att0 now fp16 (half the bytes of the old fp32 plane) — same slot budget.
#define O_HB    0ull              // bf16 [6400][384]  (h, then outm, then h2)
#define O_Q     1228800ull        // bf16 [32*12][197][32] (q, SQF folded)
#define O_K     3649536ull        // bf16 (k, SQF folded)
#define O_V     6070272ull        // fp32 v
#define O_ATT0  8491008ull        // fp16 [32*12][NN2] (29.8 MB used of slot)
#define O_X1    23393664ull       // fp32 2420736
#define O_WQKV  25814400ull       // bf16 1152x384
#define O_WPRJ  26035584ull       // bf16 384x384
#define O_WFC1  26109312ull       // bf16 1536x384
#define O_WFC2  26404224ull       // bf16 384x1536
#define O_STATS 26699136ull
#define WS_FLOATS (O_STATS + ST_TOTAL)          // ~107 MB — baseline requirement
// mid-ws tier: persisted dw output s as fp16 pairs (u32 [32*18][NN2], 89.4 MB)
#define O_SBUF  (O_STATS + ST_TOTAL)            // 26708032 (u32 slots == float slots)
#define SBUF_WORDS 22353984ull                  // 32*18*NN2
#define WS_FLOATS_MID (O_SBUF + SBUF_WORDS)     // 49062016 floats ≈ 196.2 MB

// ---- bf16x2 pack/unpack (fallback k_p3 path) ----
__device__ __forceinline__ u32 pack2(float a, float b) {
    u32 ua = __builtin_bit_cast(u32, a);
    u32 ub = __builtin_bit_cast(u32, b);
    return (ua >> 16) | (ub & 0xffff0000u);
}
__device__ __forceinline__ float unpk_lo(u32 w) { return __builtin_bit_cast(float, w << 16); }
__device__ __forceinline__ float unpk_hi(u32 w) { return __builtin_bit_cast(float, w & 0xffff0000u); }

// ---- fp16x2 pack/unpack ----
__device__ __forceinline__ u32 packh2(float a, float b) {
    fp16x2 h = __builtin_amdgcn_cvt_pkrtz(a, b);   // v_cvt_pkrtz_f16_f32
    return __builtin_bit_cast(u32, h);
}
__device__ __forceinline__ float unph_lo(u32 w) {
    fp16x2 h = __builtin_bit_cast(fp16x2, w);
    return (float)h.x;
}
__device__ __forceinline__ float unph_hi(u32 w) {
    fp16x2 h = __builtin_bit_cast(fp16x2, w);
    return (float)h.y;
}

// ---- DPP sum reduce (VALU pipe — no LDS-pipe ds_swizzle) ----
template <int CTRL>
__device__ __forceinline__ float dpp_addf(float v) {
    int x = __builtin_amdgcn_update_dpp(0, __builtin_bit_cast(int, v),
                                        CTRL, 0xF, 0xF, true);
    return v + __builtin_bit_cast(float, x);
}
__device__ __forceinline__ float red16(float v) {
    v = dpp_addf<0xB1>(v);    // quad_perm [1,0,3,2]  = xor 1
    v = dpp_addf<0x4E>(v);    // quad_perm [2,3,0,1]  = xor 2
    v = dpp_addf<0x141>(v);   // ROW_HALF_MIRROR      = pair across quads (8-group sum)
    v = dpp_addf<0x140>(v);   // ROW_MIRROR           = combine the two 8-groups (16-row sum)
    return v;
}

// ---- PACKED fp16-pair DPP reduce ----
template <int CTRL>
__device__ __forceinline__ u32 dpp_addh(u32 v) {
    int x = __builtin_amdgcn_update_dpp(0, __builtin_bit_cast(int, v),
                                        CTRL, 0xF, 0xF, true);
    fp16x2 a = __builtin_bit_cast(fp16x2, v);
    fp16x2 b = __builtin_bit_cast(fp16x2, (u32)x);
    fp16x2 c = a + b;                       // v_pk_add_f16
    return __builtin_bit_cast(u32, c);
}
__device__ __forceinline__ u32 red16h(u32 v) {
    v = dpp_addh<0xB1>(v);
    v = dpp_addh<0x4E>(v);
    v = dpp_addh<0x141>(v);
    v = dpp_addh<0x140>(v);
    return v;
}

// ============================ weight fp32 -> bf16 ========================
__global__ __launch_bounds__(256) void k_cvt(const float* __restrict__ s0,
                                             const float* __restrict__ s1,
                                             const float* __restrict__ s2,
                                             const float* __restrict__ s3,
                                             bf16* __restrict__ d0,
                                             bf16* __restrict__ d1,
                                             bf16* __restrict__ d2,
                                             bf16* __restrict__ d3) {
    const int w = blockIdx.y;
    const float* s = (w == 0) ? s0 : (w == 1) ? s1 : (w == 2) ? s2 : s3;
    bf16* d = (w == 0) ? d0 : (w == 1) ? d1 : (w == 2) ? d2 : d3;
    const int n = (w == 0) ? 442368 : (w == 1) ? 147456 : 589824;
    for (int i = blockIdx.x * 256 + threadIdx.x; i < n; i += gridDim.x * 256)
        d[i] = (bf16)s[i];
}

// ============================ LayerNorm (x*0.5) -> bf16 ==================
__global__ __launch_bounds__(384) void k_ln(const float* __restrict__ xin,
                                            const float* __restrict__ g,
                                            const float* __restrict__ bb,
                                            bf16* __restrict__ hout) {
    const int r = blockIdx.x;
    const int t = threadIdx.x;
    float v = xin[(size_t)r * DIM + t] * 0.5f;
    float s = v, sq = v * v;
#pragma unroll
    for (int off = 32; off >= 1; off >>= 1) {
        s  += __shfl_xor(s, off);
        sq += __shfl_xor(sq, off);
    }
    __shared__ float ls[6], lq[6];
    __shared__ float mv[2];
    const int wid = t >> 6;
    if ((t & 63) == 0) { ls[wid] = s; lq[wid] = sq; }
    __syncthreads();
    if (t == 0) {
        float S = 0.f, Q = 0.f;
        for (int i = 0; i < 6; ++i) { S += ls[i]; Q += lq[i]; }
        float m = S / (float)DIM;
        mv[0] = m;
        mv[1] = rsqrtf(Q / (float)DIM - m * m + EPS);
    }
    __syncthreads();
    hout[(size_t)r * DIM + t] = (bf16)((v - mv[0]) * mv[1] * g[t] + bb[t]);
}

// =============== 128x128 bf16 MFMA GEMM core: C = A[M][K] @ B[N][K]^T ====
template <int KDIM>
__device__ __forceinline__ void mgemm(const bf16* __restrict__ A,
                                      const bf16* __restrict__ B,
                                      int row0, int col0,
                                      floatx4 (&acc)[4][4]) {
    __shared__ bf16 As[128 * 32];
    __shared__ bf16 Bs[128 * 32];
    const int tid = threadIdx.x;
    const int lane = tid & 63, wave = tid >> 6;
    const int wy = wave >> 1, wx = wave & 1;
    const int quad = lane >> 4, l15 = lane & 15;
    for (int k0 = 0; k0 < KDIM; k0 += 32) {
#pragma unroll
        for (int i = 0; i < 2; ++i) {
            const int e = (i * 256 + tid) * 8;           // bf16 elem offset in tile
            const int r = e >> 5, kk = e & 31;
            __builtin_amdgcn_global_load_lds(
                (gptr_t)(A + (size_t)(row0 + r) * KDIM + k0 + kk),
                (lptr_t)(As + e), 16, 0, 0);
            __builtin_amdgcn_global_load_lds(
                (gptr_t)(B + (size_t)(col0 + r) * KDIM + k0 + kk),
                (lptr_t)(Bs + e), 16, 0, 0);
        }
        __syncthreads();
        bf16x8 af[4], bfr[4];
#pragma unroll
        for (int mi = 0; mi < 4; ++mi)
            af[mi] = *(const bf16x8*)&As[(wy * 64 + mi * 16 + l15) * 32 + quad * 8];
#pragma unroll
        for (int ni = 0; ni < 4; ++ni)
            bfr[ni] = *(const bf16x8*)&Bs[(wx * 64 + ni * 16 + l15) * 32 + quad * 8];
#pragma unroll
        for (int mi = 0; mi < 4; ++mi)
#pragma unroll
            for (int ni = 0; ni < 4; ++ni)
                acc[mi][ni] = __builtin_amdgcn_mfma_f32_16x16x32_bf16(
                    af[mi], bfr[ni], acc[mi][ni], 0, 0, 0);
        __syncthreads();
    }
}

// ============================ QKV GEMM + scatter =========================
__global__ __launch_bounds__(256) void k_qkv(const bf16* __restrict__ h,
                                             const bf16* __restrict__ w,
                                             bf16* __restrict__ qb,
                                             bf16* __restrict__ kxb,
                                             float* __restrict__ v) {
    floatx4 acc[4][4] = {};
    const int row0 = blockIdx.y * 128, col0 = blockIdx.x * 128;
    mgemm<DIM>(h, w, row0, col0, acc);
    const int lane = threadIdx.x & 63, wave = threadIdx.x >> 6;
    const int wy = wave >> 1, wx = wave & 1;
    const int quad = lane >> 4, l15 = lane & 15;
#pragma unroll
    for (int mi = 0; mi < 4; ++mi)
#pragma unroll
        for (int reg = 0; reg < 4; ++reg) {
            int r = row0 + wy * 64 + mi * 16 + quad * 4 + reg;
            if (r >= NROWS) continue;
            int b = r / NSEQ, n = r - b * NSEQ;
#pragma unroll
            for (int ni = 0; ni < 4; ++ni) {
                int o = col0 + wx * 64 + ni * 16 + l15;
                int sec = o / DIM;
                int hh = (o >> 5) % NH;
                int dd = o & 31;
                float val = acc[mi][ni][reg];
                size_t idx = ((size_t)(b * NH + hh) * NSEQ + n) * HD + dd;
                if (sec == 2)      v[idx] = val;
                else if (sec == 0) qb[idx]  = (bf16)(val * SQF);
                else               kxb[idx] = (bf16)(val * SQF);
            }
        }
}

// ============================ proj GEMM + residual =======================
__global__ __launch_bounds__(256) void k_proj(const bf16* __restrict__ outm,
                                              const bf16* __restrict__ w,
                                              const float* __restrict__ pb,
                                              const float* __restrict__ x0,
                                              float* __restrict__ x1) {
    floatx4 acc[4][4] = {};
    const int row0 = blockIdx.y * 128, col0 = blockIdx.x * 128;
    mgemm<DIM>(outm, w, row0, col0, acc);
    const int lane = threadIdx.x & 63, wave = threadIdx.x >> 6;
    const int wy = wave >> 1, wx = wave & 1;
    const int quad = lane >> 4, l15 = lane & 15;
#pragma unroll
    for (int mi = 0; mi < 4; ++mi)
#pragma unroll
        for (int reg = 0; reg < 4; ++reg) {
            int r = row0 + wy * 64 + mi * 16 + quad * 4 + reg;
            if (r >= NROWS) continue;
#pragma unroll
            for (int ni = 0; ni < 4; ++ni) {
                int o = col0 + wx * 64 + ni * 16 + l15;
                x1[(size_t)r * DIM + o] =
                    x0[(size_t)r * DIM + o] + 2.f * (acc[mi][ni][reg] + pb[o]);
            }
        }
}

// ============================ fc1 GEMM + exact GELU -> bf16 ==============
__global__ __launch_bounds__(256) void k_fc1(const bf16* __restrict__ h,
                                             const bf16* __restrict__ w,
                                             const float* __restrict__ fb,
                                             bf16* __restrict__ m1) {
    floatx4 acc[4][4] = {};
    const int row0 = blockIdx.y * 128, col0 = blockIdx.x * 128;
    mgemm<DIM>(h, w, row0, col0, acc);
    const int lane = threadIdx.x & 63, wave = threadIdx.x >> 6;
    const int wy = wave >> 1, wx = wave & 1;
    const int quad = lane >> 4, l15 = lane & 15;
#pragma unroll
    for (int mi = 0; mi < 4; ++mi)
#pragma unroll
        for (int reg = 0; reg < 4; ++reg) {
            int r = row0 + wy * 64 + mi * 16 + quad * 4 + reg;
            if (r >= NROWS) continue;
#pragma unroll
            for (int ni = 0; ni < 4; ++ni) {
                int o = col0 + wx * 64 + ni * 16 + l15;
                float z = acc[mi][ni][reg] + fb[o];
                m1[(size_t)r * MLPH + o] =
                    (bf16)(0.5f * z * (1.f + erff(z * 0.70710678118654752f)));
            }
        }
}

// ============================ fc2 GEMM + scale + residual ================
__global__ __launch_bounds__(256) void k_fc2(const bf16* __restrict__ m1,
                                             const bf16* __restrict__ w,
                                             const float* __restrict__ fb,
                                             const float* __restrict__ scch,
                                             const float* __restrict__ x1,
                                             float* __restrict__ xout) {
    floatx4 acc[4][4] = {};
    const int row0 = blockIdx.y * 128, col0 = blockIdx.x * 128;
    mgemm<MLPH>(m1, w, row0, col0, acc);
    const int lane = threadIdx.x & 63, wave = threadIdx.x >> 6;
    const int wy = wave >> 1, wx = wave & 1;
    const int quad = lane >> 4, l15 = lane & 15;
#pragma unroll
    for (int mi = 0; mi < 4; ++mi)
#pragma unroll
        for (int reg = 0; reg < 4; ++reg) {
            int r = row0 + wy * 64 + mi * 16 + quad * 4 + reg;
            if (r >= NROWS) continue;
#pragma unroll
            for (int ni = 0; ni < 4; ++ni) {
                int o = col0 + wx * 64 + ni * 16 + l15;
                xout[(size_t)r * DIM + o] =
                    x1[(size_t)r * DIM + o] + 2.f * (acc[mi][ni][reg] + fb[o]) * scch[o];
            }
        }
}

// ==================== scores via MFMA + softmax -> fp16 att0 =============
__global__ __launch_bounds__(256) void k_score(const bf16* __restrict__ qb,
                                               const bf16* __restrict__ kmat,
                                               __fp16* __restrict__ att) {
    __shared__ bf16 Ks[208 * 32];     // 13312 B, zero-padded rows 197..207
    __shared__ bf16 Qs[16 * 32];      // 1024 B
    __shared__ float Ss[16][208];     // 13312 B
    const int bh = blockIdx.y;
    const int y0 = blockIdx.x * 16;
    const int tid = threadIdx.x;
    const size_t kb = (size_t)bh * (NSEQ * HD);
    {
        const u32* ksrc = (const u32*)(kmat + kb);
        u32* kdst = (u32*)Ks;
        for (int i = tid; i < 208 * 16; i += 256)
            kdst[i] = (i < NSEQ * 16) ? ksrc[i] : 0u;
        const u32* qsrc = (const u32*)(qb + kb);
        u32* qdst = (u32*)Qs;
        for (int i = tid; i < 16 * 16; i += 256) {
            int rr = i >> 4, yy = y0 + rr;
            qdst[i] = (yy < NSEQ) ? qsrc[(size_t)yy * 16 + (i & 15)] : 0u;
        }
    }
    __syncthreads();
    {
        const int lane = tid & 63;
        const int wave = tid >> 6;
        const int l15 = lane & 15, quad = lane >> 4;
        bf16x8 af = *(const bf16x8*)&Qs[l15 * 32 + quad * 8];
        for (int t = wave; t < 13; t += 4) {
            bf16x8 bfr = *(const bf16x8*)&Ks[(t * 16 + l15) * 32 + quad * 8];
            floatx4 c = {0.f, 0.f, 0.f, 0.f};
            c = __builtin_amdgcn_mfma_f32_16x16x32_bf16(af, bfr, c, 0, 0, 0);
#pragma unroll
            for (int reg = 0; reg < 4; ++reg)
                Ss[quad * 4 + reg][t * 16 + l15] = c[reg];
        }
    }
    __syncthreads();
    const int tx = tid & 15, ty = tid >> 4;
    const int y = y0 + ty;
    if (y >= NSEQ) return;
    float sc[13];
    float mx = -1e30f;
#pragma unroll
    for (int m = 0; m < 13; ++m) {
        int x = tx + m * 16;
        float d = (x < NSEQ) ? Ss[ty][x] : -1e30f;
        sc[m] = d;
        mx = fmaxf(mx, d);
    }
#pragma unroll
    for (int off = 8; off >= 1; off >>= 1) mx = fmaxf(mx, __shfl_xor(mx, off, 16));
    float ssum = 0.f;
#pragma unroll
    for (int m = 0; m < 13; ++m) {
        int x = tx + m * 16;
        float e = (x < NSEQ) ? __expf(sc[m] - mx) : 0.f;
        sc[m] = e;
        ssum += e;
    }
#pragma unroll
    for (int off = 8; off >= 1; off >>= 1) ssum += __shfl_xor(ssum, off, 16);
    const float rinv = 1.f / ssum;
    const size_t ab = (size_t)bh * NN2 + (size_t)y * NSEQ;
#pragma unroll
    for (int m = 0; m < 13; ++m) {
        int x = tx + m * 16;
        if (x < NSEQ) att[ab + x] = (__fp16)(sc[m] * rinv);
    }
}

// ============================ channel moments of attn0 ===================
__global__ __launch_bounds__(256) void k_moments(const __fp16* __restrict__ att,
                                                 float* __restrict__ stats) {
    float mu[12] = {};
    float pr[78] = {};
    const int stride = gridDim.x * 256;
    for (int p = blockIdx.x * 256 + threadIdx.x; p < NPIX; p += stride) {
        int b = p / NN2;
        int s = p - b * NN2;
        const __fp16* base = att + (size_t)b * 12 * NN2 + s;
        float v[12];
#pragma unroll
        for (int i = 0; i < 12; ++i) v[i] = (float)base[(size_t)i * NN2];
#pragma unroll
        for (int i = 0; i < 12; ++i) mu[i] += v[i];
#pragma unroll
        for (int i = 0; i < 12; ++i)
#pragma unroll
            for (int j = i; j < 12; ++j)
                pr[i * (23 - i) / 2 + j] += v[i] * v[j];
    }
#pragma unroll
    for (int s = 0; s < 12; ++s)
#pragma unroll
        for (int off = 32; off >= 1; off >>= 1) mu[s] += __shfl_xor(mu[s], off);
#pragma unroll
    for (int s = 0; s < 78; ++s)
#pragma unroll
        for (int off = 32; off >= 1; off >>= 1) pr[s] += __shfl_xor(pr[s], off);
    __shared__ float red[4][90];
    const int lane = threadIdx.x & 63, wid = threadIdx.x >> 6;
    if (lane == 0) {
#pragma unroll
        for (int s = 0; s < 12; ++s) red[wid][s] = mu[s];
#pragma unroll
        for (int s = 0; s < 78; ++s) red[wid][12 + s] = pr[s];
    }
    __syncthreads();
    const int t = threadIdx.x;
    if (t < 90) {
        float tot = red[0][t] + red[1][t] + red[2][t] + red[3][t];
        int addr;
        if (t < 12) addr = ST_MOMSUM + t;
        else {
            int tt = t - 12;
            int i = 0;
            while (tt >= 12 - i) { tt -= 12 - i; ++i; }
            addr = ST_MOMPROD + i * 12 + (i + tt);
        }
        atomicAdd(&stats[addr], tot);
    }
}

// ============================ finalize bn1 (analytic) ====================
__global__ __launch_bounds__(64) void k_fin1(const float* __restrict__ wexp,
                                             const float* __restrict__ g1,
                                             const float* __restrict__ b1,
                                             float* __restrict__ stats) {
    int o = threadIdx.x;
    if (o >= 36) return;
    const float invM = 1.f / (float)NPIX;
    float mu[12];
#pragma unroll
    for (int i = 0; i < 12; ++i) mu[i] = stats[ST_MOMSUM + i] * invM;
    float mean = 0.f;
#pragma unroll
    for (int i = 0; i < 12; ++i) mean += wexp[o * 12 + i] * mu[i];
    float e2 = 0.f;
    for (int i = 0; i < 12; ++i)
        for (int j = 0; j < 12; ++j) {
            int a = i < j ? i : j, bj = i < j ? j : i;
            e2 += wexp[o * 12 + i] * wexp[o * 12 + j] * stats[ST_MOMPROD + a * 12 + bj] * invM;
        }
    float var = e2 - mean * mean;
    float sc = g1[o] * rsqrtf(var + EPS);
    stats[ST_SC1 + o] = sc;
    stats[ST_SH1 + o] = b1[o] - mean * sc;
}

// ====== PASS A: expand (packed f32) + bn1 + relu6 -> fp16-packed b1, =====
// ====== dw conv in v_pk_fma_f16; stats via PACKED fp16 DPP reduce    =====
template <int STORE>
__global__ __launch_bounds__(256) void k_sums2(const __fp16* __restrict__ att,
                                               const float* __restrict__ wexp,
                                               const float* __restrict__ dww,
                                               const float* __restrict__ stats,
                                               float* __restrict__ statw,
                                               u32* __restrict__ sbuf) {
    __shared__ u32  b1p[18][256];
    __shared__ floatx2 wexp2[216];   // [pp*12+i] = (wexp[2pp][i], wexp[2pp+1][i])
    __shared__ fp16x2 dw2h[162];     // [pp*9+t]  = f16 (dww[2pp][t], dww[2pp+1][t])
    __shared__ floatx2 sc1p[18], sh1p[18];
    __shared__ float red[16][73];    // [leader][72 partials]
    const int b = blockIdx.z;
    const int oy0 = blockIdx.y * 14, ox0 = blockIdx.x * 14;
    const int tid = threadIdx.x;
    for (int i = tid; i < 216; i += 256) {
        int pp = i / 12, ii = i - pp * 12;
        floatx2 t = {wexp[(2 * pp) * 12 + ii], wexp[(2 * pp + 1) * 12 + ii]};
        wexp2[i] = t;
    }
    for (int i = tid; i < 162; i += 256) {
        int pp = i / 9, t9 = i - pp * 9;
        fp16x2 t = {(__fp16)dww[(2 * pp) * 9 + t9], (__fp16)dww[(2 * pp + 1) * 9 + t9]};
        dw2h[i] = t;
    }
    if (tid < 18) {
        floatx2 a = {stats[ST_SC1 + 2 * tid], stats[ST_SC1 + 2 * tid + 1]};
        floatx2 bshift = {stats[ST_SH1 + 2 * tid], stats[ST_SH1 + 2 * tid + 1]};
        sc1p[tid] = a;
        sh1p[tid] = bshift;
    }
    const int lx = tid & 15, ly = tid >> 4;
    const int gy = oy0 - 1 + ly, gx = ox0 - 1 + lx;
    const bool valid = (gy >= 0 && gy < NSEQ && gx >= 0 && gx < NSEQ);
    float a0v[12];
#pragma unroll
    for (int i = 0; i < 12; ++i)
        a0v[i] = valid ? (float)att[(size_t)(b * 12 + i) * NN2 + (size_t)gy * NSEQ + gx] : 0.f;
    __syncthreads();
    const floatx2 vzero = {0.f, 0.f};
    const floatx2 vsix  = {6.f, 6.f};
#pragma unroll 3
    for (int pp = 0; pp < 18; ++pp) {
        floatx2 t = vzero;
#pragma unroll
        for (int i = 0; i < 12; ++i) {
            floatx2 av = {a0v[i], a0v[i]};
            t = __builtin_elementwise_fma(wexp2[pp * 12 + i], av, t);
        }
        t = __builtin_elementwise_fma(sc1p[pp], t, sh1p[pp]);
        t = __builtin_elementwise_max(t, vzero);
        t = __builtin_elementwise_min(t, vsix);
        if (!valid) t = vzero;
        b1p[pp][tid] = packh2(t.x, t.y);   // fp16 pairs
    }
    __syncthreads();
    const bool inter = (ly >= 1 && ly <= 14 && lx >= 1 && lx <= 14 &&
                        gy < NSEQ && gx < NSEQ);
    const int base = inter ? ((ly - 1) * 16 + (lx - 1)) : 0;
    const int leader = tid >> 4;
    const size_t pix = (size_t)gy * NSEQ + gx;
    const fp16x2 hzero = {(__fp16)0.f, (__fp16)0.f};
#pragma unroll 3
    for (int pp = 0; pp < 18; ++pp) {
        fp16x2 sh = hzero;
        if (inter) {
            const u32* bp = &b1p[pp][base];
#pragma unroll
            for (int dy = 0; dy < 3; ++dy)
#pragma unroll
                for (int dx = 0; dx < 3; ++dx) {
                    fp16x2 bv = __builtin_bit_cast(fp16x2, bp[dy * 16 + dx]);
                    sh = __builtin_elementwise_fma(dw2h[pp * 9 + dy * 3 + dx], bv, sh);
                }
            if (STORE)
                sbuf[((size_t)(b * 18 + pp)) * NN2 + pix] = __builtin_bit_cast(u32, sh);
        }
        fp16x2 sq = sh * sh;                              // v_pk_mul_f16
        u32 rs = red16h(__builtin_bit_cast(u32, sh));     // packed pair reduce
        u32 rq = red16h(__builtin_bit_cast(u32, sq));
        if ((tid & 15) == 0) {
            red[leader][pp * 4 + 0] = unph_lo(rs);
            red[leader][pp * 4 + 1] = unph_hi(rs);
            red[leader][pp * 4 + 2] = unph_lo(rq);
            red[leader][pp * 4 + 3] = unph_hi(rq);
        }
    }
    __syncthreads();
    if (tid < 72) {
        float tot = 0.f;
        for (int l = 0; l < 16; ++l) tot += red[l][tid];
        int pp = tid >> 2, j = tid & 3;
        int c = 2 * pp + (j & 1);
        int isq = j >> 1;
        int slot = (blockIdx.z * 225 + blockIdx.y * 15 + blockIdx.x) & 63;
        atomicAdd(&statw[(isq ? ST_SS2 : ST_S2) + slot * 36 + c], tot);
    }
}

__global__ __launch_bounds__(64) void k_fin2(const float* __restrict__ g2,
                                             const float* __restrict__ b2,
                                             float* __restrict__ stats) {
    int o = threadIdx.x;
    if (o >= 36) return;
    float S = 0.f, SS = 0.f;
    for (int sl = 0; sl < 64; ++sl) {
        S += stats[ST_S2 + sl * 36 + o];
        SS += stats[ST_SS2 + sl * 36 + o];
    }
    const float invM = 1.f / (float)NPIX;
    float m = S * invM, var = SS * invM - m * m;
    float sc = g2[o] * rsqrtf(var + EPS);
    stats[ST_SC2 + o] = sc;
    stats[ST_SH2 + o] = b2[o] - m * sc;
}

// ====== PASS B (thin, mid-ws): read persisted fp16 s, bn2+relu6+project ==
__global__ __launch_bounds__(256) void k_p3f(const __fp16* __restrict__ att,
                                             const u32* __restrict__ sbuf,
                                             const float* __restrict__ pw,
                                             const float* __restrict__ stats,
                                             float* __restrict__ datt,
                                             float* __restrict__ statw) {
    __shared__ floatx2 pw2[216];     // [k*36+ch] = (pw[2k][ch], pw[2k+1][ch]), k=c-pair
    __shared__ floatx2 sc2p[18], sh2p[18];
    __shared__ float red2[16][37];
    const int tid = threadIdx.x;
    for (int i = tid; i < 216; i += 256) {
        int k = i / 36, ch = i - k * 36;
        floatx2 t = {pw[(2 * k) * 36 + ch], pw[(2 * k + 1) * 36 + ch]};
        pw2[i] = t;
    }
    if (tid < 18) {
        floatx2 a = {stats[ST_SC2 + 2 * tid], stats[ST_SC2 + 2 * tid + 1]};
        floatx2 bshift = {stats[ST_SH2 + 2 * tid], stats[ST_SH2 + 2 * tid + 1]};
        sc2p[tid] = a;
        sh2p[tid] = bshift;
    }
    __syncthreads();
    const int p = blockIdx.x * 256 + tid;
    const bool act = p < NPIX;
    int b = 0, s = 0;
    if (act) { b = p / NN2; s = p - b * NN2; }
    const floatx2 vzero = {0.f, 0.f};
    const floatx2 vsix  = {6.f, 6.f};
    floatx2 a3p[6] = {vzero, vzero, vzero, vzero, vzero, vzero};
    float a0v[12] = {};
    if (act) {
        const u32* sb = sbuf + (size_t)b * 18 * NN2 + s;
#pragma unroll 3
        for (int pp = 0; pp < 18; ++pp) {
            u32 w = sb[(size_t)pp * NN2];
            floatx2 sv = {unph_lo(w), unph_hi(w)};
            floatx2 u = __builtin_elementwise_fma(sc2p[pp], sv, sh2p[pp]);
            u = __builtin_elementwise_max(u, vzero);
            u = __builtin_elementwise_min(u, vsix);
            floatx2 ux = {u.x, u.x};
            floatx2 uy = {u.y, u.y};
#pragma unroll
            for (int k = 0; k < 6; ++k) {
                a3p[k] = __builtin_elementwise_fma(pw2[k * 36 + 2 * pp], ux, a3p[k]);
                a3p[k] = __builtin_elementwise_fma(pw2[k * 36 + 2 * pp + 1], uy, a3p[k]);
            }
        }
        const __fp16* ab = att + (size_t)b * 12 * NN2 + s;
#pragma unroll
        for (int c = 0; c < 12; ++c) a0v[c] = (float)ab[(size_t)c * NN2];
#pragma unroll
        for (int k = 0; k < 6; ++k) {
            datt[(size_t)(b * 12 + 2 * k) * NN2 + s]     = a3p[k].x;
            datt[(size_t)(b * 12 + 2 * k + 1) * NN2 + s] = a3p[k].y;
        }
    }
    const int leader = tid >> 4;
#pragma unroll
    for (int k = 0; k < 6; ++k) {
        float v0 = a3p[k].x, v1 = a3p[k].y;
        float r30 = red16(v0);
        float r31 = red16(v1);
        float rq0 = red16(v0 * v0);
        float rq1 = red16(v1 * v1);
        float rx0 = red16(v0 * a0v[2 * k]);
        float rx1 = red16(v1 * a0v[2 * k + 1]);
        if ((tid & 15) == 0) {
            red2[leader][2 * k]          = r30;
            red2[leader][2 * k + 1]      = r31;
            red2[leader][12 + 2 * k]     = rq0;
            red2[leader][12 + 2 * k + 1] = rq1;
            red2[leader][24 + 2 * k]     = rx0;
            red2[leader][24 + 2 * k + 1] = rx1;
        }
    }
    __syncthreads();
    if (tid < 36) {
        float tot = 0.f;
        for (int l = 0; l < 16; ++l) tot += red2[l][tid];
        int slot = blockIdx.x & 63;
        atomicAdd(&statw[ST_P3 + slot * 36 + tid], tot);
    }
}

// ====== PASS B (fallback, small-ws): full recompute + fused stats =======
__global__ __launch_bounds__(256) void k_p3(const __fp16* __restrict__ att,
                                            const float* __restrict__ wexp,
                                            const float* __restrict__ dww,
                                            const float* __restrict__ pw,
                                            const float* __restrict__ stats,
                                            float* __restrict__ datt,
                                            float* __restrict__ statw) {
    __shared__ u32  b1p[18][256];
    __shared__ float wexps[432];
    __shared__ float dws[324];
    __shared__ float pws[432];
    __shared__ float sc1s[36], sh1s[36], sc2s[36], sh2s[36];
    __shared__ float red2[32][37];
    const int b = blockIdx.z;
    const int oy0 = blockIdx.y * 14, ox0 = blockIdx.x * 14;
    const int tid = threadIdx.x;
    for (int i = tid; i < 432; i += 256) { wexps[i] = wexp[i]; pws[i] = pw[i]; }
    for (int i = tid; i < 324; i += 256) dws[i] = dww[i];
    if (tid < 36) {
        sc1s[tid] = stats[ST_SC1 + tid]; sh1s[tid] = stats[ST_SH1 + tid];
        sc2s[tid] = stats[ST_SC2 + tid]; sh2s[tid] = stats[ST_SH2 + tid];
    }
    const int lx = tid & 15, ly = tid >> 4;
    const int gy = oy0 - 1 + ly, gx = ox0 - 1 + lx;
    const bool valid = (gy >= 0 && gy < NSEQ && gx >= 0 && gx < NSEQ);
    float a0v[12];
#pragma unroll
    for (int i = 0; i < 12; ++i)
        a0v[i] = valid ? (float)att[(size_t)(b * 12 + i) * NN2 + (size_t)gy * NSEQ + gx] : 0.f;
    __syncthreads();
#pragma unroll 3
    for (int pp = 0; pp < 18; ++pp) {
        float t0 = 0.f, t1 = 0.f;
#pragma unroll
        for (int i = 0; i < 12; ++i) {
            t0 = fmaf(wexps[(2 * pp) * 12 + i], a0v[i], t0);
            t1 = fmaf(wexps[(2 * pp + 1) * 12 + i], a0v[i], t1);
        }
        t0 = fminf(fmaxf(fmaf(sc1s[2 * pp], t0, sh1s[2 * pp]), 0.f), 6.f);
        t1 = fminf(fmaxf(fmaf(sc1s[2 * pp + 1], t1, sh1s[2 * pp + 1]), 0.f), 6.f);
        if (!valid) { t0 = 0.f; t1 = 0.f; }
        b1p[pp][tid] = pack2(t0, t1);
    }
    __syncthreads();
    const bool inter = (ly >= 1 && ly <= 14 && lx >= 1 && lx <= 14 &&
                        gy < NSEQ && gx < NSEQ);
    float a3v[12] = {};
    if (inter) {
        const int base = (ly - 1) * 16 + (lx - 1);
#pragma unroll 3
        for (int pp = 0; pp < 18; ++pp) {
            const u32* bp = &b1p[pp][base];
            float s0 = 0.f, s1 = 0.f;
#pragma unroll
            for (int dy = 0; dy < 3; ++dy)
#pragma unroll
                for (int dx = 0; dx < 3; ++dx) {
                    u32 w = bp[dy * 16 + dx];
                    s0 = fmaf(dws[(2 * pp) * 9 + dy * 3 + dx], unpk_lo(w), s0);
                    s1 = fmaf(dws[(2 * pp + 1) * 9 + dy * 3 + dx], unpk_hi(w), s1);
                }
            float u0 = fminf(fmaxf(fmaf(sc2s[2 * pp], s0, sh2s[2 * pp]), 0.f), 6.f);
            float u1 = fminf(fmaxf(fmaf(sc2s[2 * pp + 1], s1, sh2s[2 * pp + 1]), 0.f), 6.f);
#pragma unroll
            for (int c = 0; c < 12; ++c)
                a3v[c] = fmaf(pws[c * 36 + 2 * pp], u0,
                         fmaf(pws[c * 36 + 2 * pp + 1], u1, a3v[c]));
        }
        const size_t pix = (size_t)gy * NSEQ + gx;
#pragma unroll
        for (int c = 0; c < 12; ++c)
            datt[(size_t)(b * 12 + c) * NN2 + pix] = a3v[c];
    }
    const int leader = tid >> 3;
#pragma unroll
    for (int c = 0; c < 12; ++c) {
        float r3  = red16(a3v[c]);
        float rq  = red16(a3v[c] * a3v[c]);
        float r30 = red16(a3v[c] * a0v[c]);
        if ((tid & 7) == 0) {
            red2[leader][c]      = r3;
            red2[leader][12 + c] = rq;
            red2[leader][24 + c] = r30;
        }
    }
    __syncthreads();
    if (tid < 36) {
        float tot = 0.f;
        for (int l = 0; l < 32; l += 2) tot += red2[l][tid];
        int slot = (blockIdx.z * 225 + blockIdx.y * 15 + blockIdx.x) & 63;
        atomicAdd(&statw[ST_P3 + slot * 36 + tid], tot);
    }
}

// ============ finalize bn3 + adapt_bn -> affine alpha/beta/gamma =========
__global__ __launch_bounds__(64) void k_fin3(const float* __restrict__ g3,
                                             const float* __restrict__ b3,
                                             const float* __restrict__ ag,
                                             const float* __restrict__ ab,
                                             float* __restrict__ stats) {
    int c = threadIdx.x;
    if (c >= 12) return;
    float S3 = 0.f, S3q = 0.f, S30 = 0.f;
    for (int sl = 0; sl < 64; ++sl) {
        const float* p = stats + ST_P3 + sl * 36;
        S3 += p[c]; S3q += p[12 + c]; S30 += p[24 + c];
    }
    float S0  = stats[ST_MOMSUM + c];
    float S0q = stats[ST_MOMPROD + c * 12 + c];
    const float M = (float)NPIX;
    float m3 = S3 / M, v3 = S3q / M - m3 * m3;
    float pp = g3[c] * rsqrtf(v3 + EPS);
    float qq = b3[c] - m3 * pp;
    float my = (pp * S3 + S0) / M + qq;
    float Syq = pp * pp * S3q + S0q + qq * qq * M + 2.f * pp * S30 + 2.f * pp * qq * S3 + 2.f * qq * S0;
    float vy = Syq / M - my * my;
    float rr = ag[c] * rsqrtf(vy + EPS);
    float ss = ab[c] - my * rr;
    stats[ST_ABG + c] = rr * pp;
    stats[ST_ABG + 12 + c] = rr;
    stats[ST_ABG + 24 + c] = rr * qq + ss;
}

// ====== final attn (in-place affine) + AV via MFMA -> bf16 outm ==========
__global__ __launch_bounds__(256) void k_p4(float* __restrict__ datt,
                                            const __fp16* __restrict__ att0,
                                            const float* __restrict__ v,
                                            const float* __restrict__ stats,
                                            bf16* __restrict__ outm) {
    __shared__ bf16 Vtb[32 * 224];    // V^T: [d][x], zero-padded x>=197
    __shared__ bf16 As[16 * 224];     // av rows (bf16), zero-padded
    const int bh = blockIdx.y;
    const int b = bh / 12, hh = bh - b * 12;
    const int y0 = blockIdx.x * 16;
    const int tid = threadIdx.x;
    const size_t vb = (size_t)bh * (NSEQ * HD);
    for (int i = tid; i < 32 * 224; i += 256) {
        int x = i >> 5, d = i & 31;
        float val = (x < NSEQ) ? v[vb + (size_t)x * HD + d] : 0.f;
        Vtb[d * 224 + x] = (bf16)val;
    }
    const float alpha = stats[ST_ABG + hh];
    const float beta  = stats[ST_ABG + 12 + hh];
    const float gamma = stats[ST_ABG + 24 + hh];
    const int tx = tid & 15, ty = tid >> 4;
    const int y = y0 + ty;
    const size_t ab = (size_t)bh * NN2 + (size_t)y * NSEQ;
    As[ty * 224 + 208 + tx] = (bf16)0.f;      // pad cols 208..223
#pragma unroll
    for (int m = 0; m < 13; ++m) {
        int x = tx + m * 16;
        float av = 0.f;
        if (y < NSEQ && x < NSEQ) {
            av = alpha * datt[ab + x] + beta * (float)att0[ab + x] + gamma;
            datt[ab + x] = av;
        }
        As[ty * 224 + x] = (bf16)av;
    }
    __syncthreads();
    const int lane = tid & 63, wave = tid >> 6;
    if (wave < 2) {
        const int l15 = lane & 15, quad = lane >> 4;
        floatx4 c = {0.f, 0.f, 0.f, 0.f};
#pragma unroll
        for (int ks = 0; ks < 7; ++ks) {
            bf16x8 af  = *(const bf16x8*)&As[l15 * 224 + ks * 32 + quad * 8];
            bf16x8 bfr = *(const bf16x8*)&Vtb[(wave * 16 + l15) * 224 + ks * 32 + quad * 8];
            c = __builtin_amdgcn_mfma_f32_16x16x32_bf16(af, bfr, c, 0, 0, 0);
        }
#pragma unroll
        for (int reg = 0; reg < 4; ++reg) {
            int yy = y0 + quad * 4 + reg;
            if (yy < NSEQ)
                outm[((size_t)b * NSEQ + yy) * DIM + hh * HD + wave * 16 + l15] =
                    (bf16)c[reg];
        }
    }
}

// ========================================================================
extern "C" void kernel_launch(void* const* d_in, const int* in_sizes, int n_in,
                              void* d_out, int out_size, void* d_ws, size_t ws_size,
                              hipStream_t stream) {
    const float* x     = (const float*)d_in[0];
    const float* ln1g  = (const float*)d_in[1];
    const float* ln1b  = (const float*)d_in[2];
    const float* qkvw  = (const float*)d_in[3];
    const float* wexp  = (const float*)d_in[4];
    const float* bn1g  = (const float*)d_in[5];
    const float* bn1b  = (const float*)d_in[6];
    const float* dww   = (const float*)d_in[7];
    const float* bn2g  = (const float*)d_in[8];
    const float* bn2b  = (const float*)d_in[9];
    const float* prow  = (const float*)d_in[10];
    const float* bn3g  = (const float*)d_in[11];
    const float* bn3b  = (const float*)d_in[12];
    const float* abng  = (const float*)d_in[13];
    const float* abnb  = (const float*)d_in[14];
    const float* projw = (const float*)d_in[15];
    const float* projb = (const float*)d_in[16];
    const float* ln2g  = (const float*)d_in[17];
    const float* ln2b  = (const float*)d_in[18];
    const float* fc1w  = (const float*)d_in[19];
    const float* fc1b  = (const float*)d_in[20];
    const float* fc2w  = (const float*)d_in[21];
    const float* fc2b  = (const float*)d_in[22];
    const float* scch  = (const float*)d_in[23];

    if (ws_size < WS_FLOATS * sizeof(float)) return;   // base requirement ~107 MB
    const bool mid = ws_size >= WS_FLOATS_MID * sizeof(float);  // ~196 MB tier

    float* W     = (float*)d_ws;
    bf16*  hb    = (bf16*)(W + O_HB);     // h, then outm, then h2 (sequential)
    bf16*  qbv   = (bf16*)(W + O_Q);      // bf16 q (SQF folded)
    bf16*  kxb   = (bf16*)(W + O_K);      // bf16 k (SQF folded)
    float* v     = W + O_V;
    __fp16* att0 = (__fp16*)(W + O_ATT0); // fp16 softmax output (internal)
    float* x1    = W + O_X1;
    bf16*  m1    = (bf16*)(W + O_ATT0);   // alias: att0 dead after k_p4
    bf16*  wqkvb = (bf16*)(W + O_WQKV);
    bf16*  wprjb = (bf16*)(W + O_WPRJ);
    bf16*  wfc1b = (bf16*)(W + O_WFC1);
    bf16*  wfc2b = (bf16*)(W + O_WFC2);
    float* stats = W + O_STATS;
    u32*   sbuf  = (u32*)(W + O_SBUF);    // only valid if mid

    float* xout = (float*)d_out;
    float* datt = xout + XSIZE;

    (void)hipMemsetAsync(stats, 0, ST_TOTAL * sizeof(float), stream);
    k_cvt<<<dim3(288, 4), 256, 0, stream>>>(qkvw, projw, fc1w, fc2w,
                                            wqkvb, wprjb, wfc1b, wfc2b);
    k_ln<<<NROWS, 384, 0, stream>>>(x, ln1g, ln1b, hb);
    k_qkv<<<dim3(9, 50), 256, 0, stream>>>(hb, wqkvb, qbv, kxb, v);
    k_score<<<dim3(13, 384), 256, 0, stream>>>(qbv, kxb, att0);
    k_moments<<<512, 256, 0, stream>>>(att0, stats);
    k_fin1<<<1, 64, 0, stream>>>(wexp, bn1g, bn1b, stats);
    if (mid) {
        k_sums2<1><<<dim3(15, 15, 32), 256, 0, stream>>>(att0, wexp, dww, stats, stats, sbuf);
        k_fin2<<<1, 64, 0, stream>>>(bn2g, bn2b, stats);
        k_p3f<<<(NPIX + 255) / 256, 256, 0, stream>>>(att0, sbuf, prow, stats, datt, stats);
    } else {
        k_sums2<0><<<dim3(15, 15, 32), 256, 0, stream>>>(att0, wexp, dww, stats, stats, nullptr);
        k_fin2<<<1, 64, 0, stream>>>(bn2g, bn2b, stats);
        k_p3<<<dim3(15, 15, 32), 256, 0, stream>>>(att0, wexp, dww, prow, stats, datt, stats);
    }
    k_fin3<<<1, 64, 0, stream>>>(bn3g, bn3b, abng, abnb, stats);
    k_p4<<<dim3(13, 384), 256, 0, stream>>>(datt, att0, v, stats, hb);
    k_proj<<<dim3(3, 50), 256, 0, stream>>>(hb, wprjb, projb, x, x1);
    k_ln<<<NROWS, 384, 0, stream>>>(x1, ln2g, ln2b, hb);
    k_fc1<<<dim3(12, 50), 256, 0, stream>>>(hb, wfc1b, fc1b, m1);
    k_fc2<<<dim3(3, 50), 256, 0, stream>>>(m1, wfc2b, fc2b, scch, x1, xout);
}

// Round 18
// 487.275 us; speedup vs baseline: 1.0543x; 1.0236x over previous
//
#include <hip/hip_runtime.h>
#include <math.h>

#define EPS   1e-5f
#define NSEQ  197
#define DIM   384
#define NH    12
#define HD    32
#define MLPH  1536
#define NN2   38809          // 197*197
#define NROWS 6304           // 32*197
#define NPIX  1241888        // 32*38809
#define XSIZE 2420736        // 32*197*384 — exact size of output 0
#define SQF   0.4204482076268572f   // 32^(-0.25)

typedef __bf16 bf16;
typedef __attribute__((ext_vector_type(2))) __fp16 fp16x2;
typedef __attribute__((ext_vector_type(2))) float floatx2;
typedef __attribute__((ext_vector_type(8))) __bf16 bf16x8;
typedef __attribute__((ext_vector_type(4))) float floatx4;
typedef unsigned int u32;
typedef const __attribute__((address_space(1))) u32* gptr_t;
typedef __attribute__((address_space(3))) u32* lptr_t;

// ---- stats scratch layout (floats, inside ws) ----
#define ST_MOMSUM  0      // 12
#define ST_MOMPROD 16     // 144 (i<=j at i*12+j)
#define ST_SC1     160    // 36
#define ST_SH1     200    // 36
#define ST_S2      256    // 64*36
#define ST_SS2     2560   // 64*36
#define ST_SC2     4864   // 36
#define ST_SH2     4900   // 36
#define ST_P3      4992   // 64*36 (S3[12],S3q[12],S30[12] per slot)
#define ST_ABG     8832   // 36 (alpha,beta,gamma)
#define ST_TOTAL   8896

// ---- workspace offsets (float slots) ----
// O_ATT0 slot: first half = fp16 att0, second half = fp16 a3 staging.
#define O_HB    0ull              // bf16 [6400][384]  (h, then outm, then h2)
#define O_Q     1228800ull        // bf16 [32*12][197][32] (q, SQF folded)
#define O_K     3649536ull        // bf16 (k, SQF folded)
#define O_V     6070272ull        // fp32 v
#define O_ATT0  8491008ull        // fp16 att0 (29.8MB) + fp16 a3 (29.8MB)
#define O_X1    23393664ull       // fp32 2420736
#define O_WQKV  25814400ull       // bf16 1152x384
#define O_WPRJ  26035584ull       // bf16 384x384
#define O_WFC1  26109312ull       // bf16 1536x384
#define O_WFC2  26404224ull       // bf16 384x1536
#define O_STATS 26699136ull
#define WS_FLOATS (O_STATS + ST_TOTAL)          // ~107 MB — baseline requirement
// mid-ws tier: persisted dw output s as fp16 pairs (u32 [32*18][NN2], 89.4 MB)
#define O_SBUF  (O_STATS + ST_TOTAL)            // 26708032 (u32 slots == float slots)
#define SBUF_WORDS 22353984ull                  // 32*18*NN2
#define WS_FLOATS_MID (O_SBUF + SBUF_WORDS)     // 49062016 floats ≈ 196.2 MB

// ---- bf16x2 pack/unpack (fallback k_p3 path) ----
__device__ __forceinline__ u32 pack2(float a, float b) {
    u32 ua = __builtin_bit_cast(u32, a);
    u32 ub = __builtin_bit_cast(u32, b);
    return (ua >> 16) | (ub & 0xffff0000u);
}
__device__ __forceinline__ float unpk_lo(u32 w) { return __builtin_bit_cast(float, w << 16); }
__device__ __forceinline__ float unpk_hi(u32 w) { return __builtin_bit_cast(float, w & 0xffff0000u); }

// ---- fp16x2 pack/unpack ----
__device__ __forceinline__ u32 packh2(float a, float b) {
    fp16x2 h = __builtin_amdgcn_cvt_pkrtz(a, b);   // v_cvt_pkrtz_f16_f32
    return __builtin_bit_cast(u32, h);
}
__device__ __forceinline__ float unph_lo(u32 w) {
    fp16x2 h = __builtin_bit_cast(fp16x2, w);
    return (float)h.x;
}
__device__ __forceinline__ float unph_hi(u32 w) {
    fp16x2 h = __builtin_bit_cast(fp16x2, w);
    return (float)h.y;
}

// ---- DPP sum reduce (VALU pipe — no LDS-pipe ds_swizzle) ----
template <int CTRL>
__device__ __forceinline__ float dpp_addf(float v) {
    int x = __builtin_amdgcn_update_dpp(0, __builtin_bit_cast(int, v),
                                        CTRL, 0xF, 0xF, true);
    return v + __builtin_bit_cast(float, x);
}
__device__ __forceinline__ float red16(float v) {
    v = dpp_addf<0xB1>(v);    // quad_perm [1,0,3,2]  = xor 1
    v = dpp_addf<0x4E>(v);    // quad_perm [2,3,0,1]  = xor 2
    v = dpp_addf<0x141>(v);   // ROW_HALF_MIRROR      = pair across quads (8-group sum)
    v = dpp_addf<0x140>(v);   // ROW_MIRROR           = combine the two 8-groups (16-row sum)
    return v;
}

// ---- PACKED fp16-pair DPP reduce ----
template <int CTRL>
__device__ __forceinline__ u32 dpp_addh(u32 v) {
    int x = __builtin_amdgcn_update_dpp(0, __builtin_bit_cast(int, v),
                                        CTRL, 0xF, 0xF, true);
    fp16x2 a = __builtin_bit_cast(fp16x2, v);
    fp16x2 b = __builtin_bit_cast(fp16x2, (u32)x);
    fp16x2 c = a + b;                       // v_pk_add_f16
    return __builtin_bit_cast(u32, c);
}
__device__ __forceinline__ u32 red16h(u32 v) {
    v = dpp_addh<0xB1>(v);
    v = dpp_addh<0x4E>(v);
    v = dpp_addh<0x141>(v);
    v = dpp_addh<0x140>(v);
    return v;
}

// ---- DPP lane move (within 16-lane row); bound_ctrl: OOB -> 0 ----
// 0x111 = row_shr:1 (lane i <- lane i-1) ; 0x101 = row_shl:1 (lane i <- i+1)
template <int CTRL>
__device__ __forceinline__ u32 dppmov(u32 v) {
    return (u32)__builtin_amdgcn_update_dpp(0, (int)v, CTRL, 0xF, 0xF, true);
}

// ============================ weight fp32 -> bf16 ========================
__global__ __launch_bounds__(256) void k_cvt(const float* __restrict__ s0,
                                             const float* __restrict__ s1,
                                             const float* __restrict__ s2,
                                             const float* __restrict__ s3,
                                             bf16* __restrict__ d0,
                                             bf16* __restrict__ d1,
                                             bf16* __restrict__ d2,
                                             bf16* __restrict__ d3) {
    const int w = blockIdx.y;
    const float* s = (w == 0) ? s0 : (w == 1) ? s1 : (w == 2) ? s2 : s3;
    bf16* d = (w == 0) ? d0 : (w == 1) ? d1 : (w == 2) ? d2 : d3;
    const int n = (w == 0) ? 442368 : (w == 1) ? 147456 : 589824;
    for (int i = blockIdx.x * 256 + threadIdx.x; i < n; i += gridDim.x * 256)
        d[i] = (bf16)s[i];
}

// ============================ LayerNorm (x*0.5) -> bf16 ==================
__global__ __launch_bounds__(384) void k_ln(const float* __restrict__ xin,
                                            const float* __restrict__ g,
                                            const float* __restrict__ bb,
                                            bf16* __restrict__ hout) {
    const int r = blockIdx.x;
    const int t = threadIdx.x;
    float v = xin[(size_t)r * DIM + t] * 0.5f;
    float s = v, sq = v * v;
#pragma unroll
    for (int off = 32; off >= 1; off >>= 1) {
        s  += __shfl_xor(s, off);
        sq += __shfl_xor(sq, off);
    }
    __shared__ float ls[6], lq[6];
    __shared__ float mv[2];
    const int wid = t >> 6;
    if ((t & 63) == 0) { ls[wid] = s; lq[wid] = sq; }
    __syncthreads();
    if (t == 0) {
        float S = 0.f, Q = 0.f;
        for (int i = 0; i < 6; ++i) { S += ls[i]; Q += lq[i]; }
        float m = S / (float)DIM;
        mv[0] = m;
        mv[1] = rsqrtf(Q / (float)DIM - m * m + EPS);
    }
    __syncthreads();
    hout[(size_t)r * DIM + t] = (bf16)((v - mv[0]) * mv[1] * g[t] + bb[t]);
}

// =============== 128x128 bf16 MFMA GEMM core: C = A[M][K] @ B[N][K]^T ====
template <int KDIM>
__device__ __forceinline__ void mgemm(const bf16* __restrict__ A,
                                      const bf16* __restrict__ B,
                                      int row0, int col0,
                                      floatx4 (&acc)[4][4]) {
    __shared__ bf16 As[128 * 32];
    __shared__ bf16 Bs[128 * 32];
    const int tid = threadIdx.x;
    const int lane = tid & 63, wave = tid >> 6;
    const int wy = wave >> 1, wx = wave & 1;
    const int quad = lane >> 4, l15 = lane & 15;
    for (int k0 = 0; k0 < KDIM; k0 += 32) {
#pragma unroll
        for (int i = 0; i < 2; ++i) {
            const int e = (i * 256 + tid) * 8;           // bf16 elem offset in tile
            const int r = e >> 5, kk = e & 31;
            __builtin_amdgcn_global_load_lds(
                (gptr_t)(A + (size_t)(row0 + r) * KDIM + k0 + kk),
                (lptr_t)(As + e), 16, 0, 0);
            __builtin_amdgcn_global_load_lds(
                (gptr_t)(B + (size_t)(col0 + r) * KDIM + k0 + kk),
                (lptr_t)(Bs + e), 16, 0, 0);
        }
        __syncthreads();
        bf16x8 af[4], bfr[4];
#pragma unroll
        for (int mi = 0; mi < 4; ++mi)
            af[mi] = *(const bf16x8*)&As[(wy * 64 + mi * 16 + l15) * 32 + quad * 8];
#pragma unroll
        for (int ni = 0; ni < 4; ++ni)
            bfr[ni] = *(const bf16x8*)&Bs[(wx * 64 + ni * 16 + l15) * 32 + quad * 8];
#pragma unroll
        for (int mi = 0; mi < 4; ++mi)
#pragma unroll
            for (int ni = 0; ni < 4; ++ni)
                acc[mi][ni] = __builtin_amdgcn_mfma_f32_16x16x32_bf16(
                    af[mi], bfr[ni], acc[mi][ni], 0, 0, 0);
        __syncthreads();
    }
}

// ============================ QKV GEMM + scatter =========================
__global__ __launch_bounds__(256) void k_qkv(const bf16* __restrict__ h,
                                             const bf16* __restrict__ w,
                                             bf16* __restrict__ qb,
                                             bf16* __restrict__ kxb,
                                             float* __restrict__ v) {
    floatx4 acc[4][4] = {};
    const int row0 = blockIdx.y * 128, col0 = blockIdx.x * 128;
    mgemm<DIM>(h, w, row0, col0, acc);
    const int lane = threadIdx.x & 63, wave = threadIdx.x >> 6;
    const int wy = wave >> 1, wx = wave & 1;
    const int quad = lane >> 4, l15 = lane & 15;
#pragma unroll
    for (int mi = 0; mi < 4; ++mi)
#pragma unroll
        for (int reg = 0; reg < 4; ++reg) {
            int r = row0 + wy * 64 + mi * 16 + quad * 4 + reg;
            if (r >= NROWS) continue;
            int b = r / NSEQ, n = r - b * NSEQ;
#pragma unroll
            for (int ni = 0; ni < 4; ++ni) {
                int o = col0 + wx * 64 + ni * 16 + l15;
                int sec = o / DIM;
                int hh = (o >> 5) % NH;
                int dd = o & 31;
                float val = acc[mi][ni][reg];
                size_t idx = ((size_t)(b * NH + hh) * NSEQ + n) * HD + dd;
                if (sec == 2)      v[idx] = val;
                else if (sec == 0) qb[idx]  = (bf16)(val * SQF);
                else               kxb[idx] = (bf16)(val * SQF);
            }
        }
}

// ============================ proj GEMM + residual =======================
__global__ __launch_bounds__(256) void k_proj(const bf16* __restrict__ outm,
                                              const bf16* __restrict__ w,
                                              const float* __restrict__ pb,
                                              const float* __restrict__ x0,
                                              float* __restrict__ x1) {
    floatx4 acc[4][4] = {};
    const int row0 = blockIdx.y * 128, col0 = blockIdx.x * 128;
    mgemm<DIM>(outm, w, row0, col0, acc);
    const int lane = threadIdx.x & 63, wave = threadIdx.x >> 6;
    const int wy = wave >> 1, wx = wave & 1;
    const int quad = lane >> 4, l15 = lane & 15;
#pragma unroll
    for (int mi = 0; mi < 4; ++mi)
#pragma unroll
        for (int reg = 0; reg < 4; ++reg) {
            int r = row0 + wy * 64 + mi * 16 + quad * 4 + reg;
            if (r >= NROWS) continue;
#pragma unroll
            for (int ni = 0; ni < 4; ++ni) {
                int o = col0 + wx * 64 + ni * 16 + l15;
                x1[(size_t)r * DIM + o] =
                    x0[(size_t)r * DIM + o] + 2.f * (acc[mi][ni][reg] + pb[o]);
            }
        }
}

// ============================ fc1 GEMM + exact GELU -> bf16 ==============
__global__ __launch_bounds__(256) void k_fc1(const bf16* __restrict__ h,
                                             const bf16* __restrict__ w,
                                             const float* __restrict__ fb,
                                             bf16* __restrict__ m1) {
    floatx4 acc[4][4] = {};
    const int row0 = blockIdx.y * 128, col0 = blockIdx.x * 128;
    mgemm<DIM>(h, w, row0, col0, acc);
    const int lane = threadIdx.x & 63, wave = threadIdx.x >> 6;
    const int wy = wave >> 1, wx = wave & 1;
    const int quad = lane >> 4, l15 = lane & 15;
#pragma unroll
    for (int mi = 0; mi < 4; ++mi)
#pragma unroll
        for (int reg = 0; reg < 4; ++reg) {
            int r = row0 + wy * 64 + mi * 16 + quad * 4 + reg;
            if (r >= NROWS) continue;
#pragma unroll
            for (int ni = 0; ni < 4; ++ni) {
                int o = col0 + wx * 64 + ni * 16 + l15;
                float z = acc[mi][ni][reg] + fb[o];
                m1[(size_t)r * MLPH + o] =
                    (bf16)(0.5f * z * (1.f + erff(z * 0.70710678118654752f)));
            }
        }
}

// ============================ fc2 GEMM + scale + residual ================
__global__ __launch_bounds__(256) void k_fc2(const bf16* __restrict__ m1,
                                             const bf16* __restrict__ w,
                                             const float* __restrict__ fb,
                                             const float* __restrict__ scch,
                                             const float* __restrict__ x1,
                                             float* __restrict__ xout) {
    floatx4 acc[4][4] = {};
    const int row0 = blockIdx.y * 128, col0 = blockIdx.x * 128;
    mgemm<MLPH>(m1, w, row0, col0, acc);
    const int lane = threadIdx.x & 63, wave = threadIdx.x >> 6;
    const int wy = wave >> 1, wx = wave & 1;
    const int quad = lane >> 4, l15 = lane & 15;
#pragma unroll
    for (int mi = 0; mi < 4; ++mi)
#pragma unroll
        for (int reg = 0; reg < 4; ++reg) {
            int r = row0 + wy * 64 + mi * 16 + quad * 4 + reg;
            if (r >= NROWS) continue;
#pragma unroll
            for (int ni = 0; ni < 4; ++ni) {
                int o = col0 + wx * 64 + ni * 16 + l15;
                xout[(size_t)r * DIM + o] =
                    x1[(size_t)r * DIM + o] + 2.f * (acc[mi][ni][reg] + fb[o]) * scch[o];
            }
        }
}

// ==================== scores via MFMA + softmax -> fp16 att0 =============
__global__ __launch_bounds__(256) void k_score(const bf16* __restrict__ qb,
                                               const bf16* __restrict__ kmat,
                                               __fp16* __restrict__ att) {
    __shared__ bf16 Ks[208 * 32];     // 13312 B, zero-padded rows 197..207
    __shared__ bf16 Qs[16 * 32];      // 1024 B
    __shared__ float Ss[16][208];     // 13312 B
    const int bh = blockIdx.y;
    const int y0 = blockIdx.x * 16;
    const int tid = threadIdx.x;
    const size_t kb = (size_t)bh * (NSEQ * HD);
    {
        const u32* ksrc = (const u32*)(kmat + kb);
        u32* kdst = (u32*)Ks;
        for (int i = tid; i < 208 * 16; i += 256)
            kdst[i] = (i < NSEQ * 16) ? ksrc[i] : 0u;
        const u32* qsrc = (const u32*)(qb + kb);
        u32* qdst = (u32*)Qs;
        for (int i = tid; i < 16 * 16; i += 256) {
            int rr = i >> 4, yy = y0 + rr;
            qdst[i] = (yy < NSEQ) ? qsrc[(size_t)yy * 16 + (i & 15)] : 0u;
        }
    }
    __syncthreads();
    {
        const int lane = tid & 63;
        const int wave = tid >> 6;
        const int l15 = lane & 15, quad = lane >> 4;
        bf16x8 af = *(const bf16x8*)&Qs[l15 * 32 + quad * 8];
        for (int t = wave; t < 13; t += 4) {
            bf16x8 bfr = *(const bf16x8*)&Ks[(t * 16 + l15) * 32 + quad * 8];
            floatx4 c = {0.f, 0.f, 0.f, 0.f};
            c = __builtin_amdgcn_mfma_f32_16x16x32_bf16(af, bfr, c, 0, 0, 0);
#pragma unroll
            for (int reg = 0; reg < 4; ++reg)
                Ss[quad * 4 + reg][t * 16 + l15] = c[reg];
        }
    }
    __syncthreads();
    const int tx = tid & 15, ty = tid >> 4;
    const int y = y0 + ty;
    if (y >= NSEQ) return;
    float sc[13];
    float mx = -1e30f;
#pragma unroll
    for (int m = 0; m < 13; ++m) {
        int x = tx + m * 16;
        float d = (x < NSEQ) ? Ss[ty][x] : -1e30f;
        sc[m] = d;
        mx = fmaxf(mx, d);
    }
#pragma unroll
    for (int off = 8; off >= 1; off >>= 1) mx = fmaxf(mx, __shfl_xor(mx, off, 16));
    float ssum = 0.f;
#pragma unroll
    for (int m = 0; m < 13; ++m) {
        int x = tx + m * 16;
        float e = (x < NSEQ) ? __expf(sc[m] - mx) : 0.f;
        sc[m] = e;
        ssum += e;
    }
#pragma unroll
    for (int off = 8; off >= 1; off >>= 1) ssum += __shfl_xor(ssum, off, 16);
    const float rinv = 1.f / ssum;
    const size_t ab = (size_t)bh * NN2 + (size_t)y * NSEQ;
#pragma unroll
    for (int m = 0; m < 13; ++m) {
        int x = tx + m * 16;
        if (x < NSEQ) att[ab + x] = (__fp16)(sc[m] * rinv);
    }
}

// ============================ channel moments of attn0 ===================
__global__ __launch_bounds__(256) void k_moments(const __fp16* __restrict__ att,
                                                 float* __restrict__ stats) {
    float mu[12] = {};
    float pr[78] = {};
    const int stride = gridDim.x * 256;
    for (int p = blockIdx.x * 256 + threadIdx.x; p < NPIX; p += stride) {
        int b = p / NN2;
        int s = p - b * NN2;
        const __fp16* base = att + (size_t)b * 12 * NN2 + s;
        float v[12];
#pragma unroll
        for (int i = 0; i < 12; ++i) v[i] = (float)base[(size_t)i * NN2];
#pragma unroll
        for (int i = 0; i < 12; ++i) mu[i] += v[i];
#pragma unroll
        for (int i = 0; i < 12; ++i)
#pragma unroll
            for (int j = i; j < 12; ++j)
                pr[i * (23 - i) / 2 + j] += v[i] * v[j];
    }
#pragma unroll
    for (int s = 0; s < 12; ++s)
#pragma unroll
        for (int off = 32; off >= 1; off >>= 1) mu[s] += __shfl_xor(mu[s], off);
#pragma unroll
    for (int s = 0; s < 78; ++s)
#pragma unroll
        for (int off = 32; off >= 1; off >>= 1) pr[s] += __shfl_xor(pr[s], off);
    __shared__ float red[4][90];
    const int lane = threadIdx.x & 63, wid = threadIdx.x >> 6;
    if (lane == 0) {
#pragma unroll
        for (int s = 0; s < 12; ++s) red[wid][s] = mu[s];
#pragma unroll
        for (int s = 0; s < 78; ++s) red[wid][12 + s] = pr[s];
    }
    __syncthreads();
    const int t = threadIdx.x;
    if (t < 90) {
        float tot = red[0][t] + red[1][t] + red[2][t] + red[3][t];
        int addr;
        if (t < 12) addr = ST_MOMSUM + t;
        else {
            int tt = t - 12;
            int i = 0;
            while (tt >= 12 - i) { tt -= 12 - i; ++i; }
            addr = ST_MOMPROD + i * 12 + (i + tt);
        }
        atomicAdd(&stats[addr], tot);
    }
}

// ============================ finalize bn1 (analytic) ====================
__global__ __launch_bounds__(64) void k_fin1(const float* __restrict__ wexp,
                                             const float* __restrict__ g1,
                                             const float* __restrict__ b1,
                                             float* __restrict__ stats) {
    int o = threadIdx.x;
    if (o >= 36) return;
    const float invM = 1.f / (float)NPIX;
    float mu[12];
#pragma unroll
    for (int i = 0; i < 12; ++i) mu[i] = stats[ST_MOMSUM + i] * invM;
    float mean = 0.f;
#pragma unroll
    for (int i = 0; i < 12; ++i) mean += wexp[o * 12 + i] * mu[i];
    float e2 = 0.f;
    for (int i = 0; i < 12; ++i)
        for (int j = 0; j < 12; ++j) {
            int a = i < j ? i : j, bj = i < j ? j : i;
            e2 += wexp[o * 12 + i] * wexp[o * 12 + j] * stats[ST_MOMPROD + a * 12 + bj] * invM;
        }
    float var = e2 - mean * mean;
    float sc = g1[o] * rsqrtf(var + EPS);
    stats[ST_SC1 + o] = sc;
    stats[ST_SH1 + o] = b1[o] - mean * sc;
}

// ====== PASS A: expand (packed f32) + bn1 + relu6 -> fp16-packed b1, =====
// ====== dw conv: 3 center-column ds_reads + DPP lane-sharing for the =====
// ====== left/right columns (DS 162->54 per thread); pk_fma_f16 conv. =====
template <int STORE>
__global__ __launch_bounds__(256) void k_sums2(const __fp16* __restrict__ att,
                                               const float* __restrict__ wexp,
                                               const float* __restrict__ dww,
                                               const float* __restrict__ stats,
                                               float* __restrict__ statw,
                                               u32* __restrict__ sbuf) {
    __shared__ u32  b1p[18][256];
    __shared__ floatx2 wexp2[216];   // [pp*12+i] = (wexp[2pp][i], wexp[2pp+1][i])
    __shared__ fp16x2 dw2h[162];     // [pp*9+t]  = f16 (dww[2pp][t], dww[2pp+1][t])
    __shared__ floatx2 sc1p[18], sh1p[18];
    __shared__ float red[16][73];    // [leader][72 partials]
    const int b = blockIdx.z;
    const int oy0 = blockIdx.y * 14, ox0 = blockIdx.x * 14;
    const int tid = threadIdx.x;
    for (int i = tid; i < 216; i += 256) {
        int pp = i / 12, ii = i - pp * 12;
        floatx2 t = {wexp[(2 * pp) * 12 + ii], wexp[(2 * pp + 1) * 12 + ii]};
        wexp2[i] = t;
    }
    for (int i = tid; i < 162; i += 256) {
        int pp = i / 9, t9 = i - pp * 9;
        fp16x2 t = {(__fp16)dww[(2 * pp) * 9 + t9], (__fp16)dww[(2 * pp + 1) * 9 + t9]};
        dw2h[i] = t;
    }
    if (tid < 18) {
        floatx2 a = {stats[ST_SC1 + 2 * tid], stats[ST_SC1 + 2 * tid + 1]};
        floatx2 bshift = {stats[ST_SH1 + 2 * tid], stats[ST_SH1 + 2 * tid + 1]};
        sc1p[tid] = a;
        sh1p[tid] = bshift;
    }
    const int lx = tid & 15, ly = tid >> 4;
    const int gy = oy0 - 1 + ly, gx = ox0 - 1 + lx;
    const bool valid = (gy >= 0 && gy < NSEQ && gx >= 0 && gx < NSEQ);
    float a0v[12];
#pragma unroll
    for (int i = 0; i < 12; ++i)
        a0v[i] = valid ? (float)att[(size_t)(b * 12 + i) * NN2 + (size_t)gy * NSEQ + gx] : 0.f;
    __syncthreads();
    const floatx2 vzero = {0.f, 0.f};
    const floatx2 vsix  = {6.f, 6.f};
#pragma unroll 3
    for (int pp = 0; pp < 18; ++pp) {
        floatx2 t = vzero;
#pragma unroll
        for (int i = 0; i < 12; ++i) {
            floatx2 av = {a0v[i], a0v[i]};
            t = __builtin_elementwise_fma(wexp2[pp * 12 + i], av, t);
        }
        t = __builtin_elementwise_fma(sc1p[pp], t, sh1p[pp]);
        t = __builtin_elementwise_max(t, vzero);
        t = __builtin_elementwise_min(t, vsix);
        if (!valid) t = vzero;
        b1p[pp][tid] = packh2(t.x, t.y);   // fp16 pairs
    }
    __syncthreads();
    // convrow is uniform across each 16-lane DPP row (ly constant per row),
    // so all source lanes for row_shr/row_shl are active.
    const bool convrow = (ly >= 1 && ly <= 14);
    const bool inter = (convrow && lx >= 1 && lx <= 14 && gy < NSEQ && gx < NSEQ);
    const int leader = tid >> 4;
    const size_t pix = (size_t)gy * NSEQ + gx;
    const fp16x2 hzero = {(__fp16)0.f, (__fp16)0.f};
#pragma unroll 3
    for (int pp = 0; pp < 18; ++pp) {
        fp16x2 sh = hzero;
        if (convrow) {
            u32 c0 = b1p[pp][(ly - 1) * 16 + lx];
            u32 c1 = b1p[pp][ ly      * 16 + lx];
            u32 c2 = b1p[pp][(ly + 1) * 16 + lx];
            u32 l0 = dppmov<0x111>(c0), r0 = dppmov<0x101>(c0);
            u32 l1 = dppmov<0x111>(c1), r1 = dppmov<0x101>(c1);
            u32 l2 = dppmov<0x111>(c2), r2 = dppmov<0x101>(c2);
            const fp16x2* w9 = &dw2h[pp * 9];
            sh = __builtin_elementwise_fma(w9[0], __builtin_bit_cast(fp16x2, l0), sh);
            sh = __builtin_elementwise_fma(w9[1], __builtin_bit_cast(fp16x2, c0), sh);
            sh = __builtin_elementwise_fma(w9[2], __builtin_bit_cast(fp16x2, r0), sh);
            sh = __builtin_elementwise_fma(w9[3], __builtin_bit_cast(fp16x2, l1), sh);
            sh = __builtin_elementwise_fma(w9[4], __builtin_bit_cast(fp16x2, c1), sh);
            sh = __builtin_elementwise_fma(w9[5], __builtin_bit_cast(fp16x2, r1), sh);
            sh = __builtin_elementwise_fma(w9[6], __builtin_bit_cast(fp16x2, l2), sh);
            sh = __builtin_elementwise_fma(w9[7], __builtin_bit_cast(fp16x2, c2), sh);
            sh = __builtin_elementwise_fma(w9[8], __builtin_bit_cast(fp16x2, r2), sh);
            if (!inter) sh = hzero;
            if (STORE && inter)
                sbuf[((size_t)(b * 18 + pp)) * NN2 + pix] = __builtin_bit_cast(u32, sh);
        }
        fp16x2 sq = sh * sh;                              // v_pk_mul_f16
        u32 rs = red16h(__builtin_bit_cast(u32, sh));     // packed pair reduce
        u32 rq = red16h(__builtin_bit_cast(u32, sq));
        if ((tid & 15) == 0) {
            red[leader][pp * 4 + 0] = unph_lo(rs);
            red[leader][pp * 4 + 1] = unph_hi(rs);
            red[leader][pp * 4 + 2] = unph_lo(rq);
            red[leader][pp * 4 + 3] = unph_hi(rq);
        }
    }
    __syncthreads();
    if (tid < 72) {
        float tot = 0.f;
        for (int l = 0; l < 16; ++l) tot += red[l][tid];
        int pp = tid >> 2, j = tid & 3;
        int c = 2 * pp + (j & 1);
        int isq = j >> 1;
        int slot = (blockIdx.z * 225 + blockIdx.y * 15 + blockIdx.x) & 63;
        atomicAdd(&statw[(isq ? ST_SS2 : ST_S2) + slot * 36 + c], tot);
    }
}

__global__ __launch_bounds__(64) void k_fin2(const float* __restrict__ g2,
                                             const float* __restrict__ b2,
                                             float* __restrict__ stats) {
    int o = threadIdx.x;
    if (o >= 36) return;
    float S = 0.f, SS = 0.f;
    for (int sl = 0; sl < 64; ++sl) {
        S += stats[ST_S2 + sl * 36 + o];
        SS += stats[ST_SS2 + sl * 36 + o];
    }
    const float invM = 1.f / (float)NPIX;
    float m = S * invM, var = SS * invM - m * m;
    float sc = g2[o] * rsqrtf(var + EPS);
    stats[ST_SC2 + o] = sc;
    stats[ST_SH2 + o] = b2[o] - m * sc;
}

// ====== PASS B (thin, mid-ws): read persisted fp16 s, bn2+relu6+project ==
// a3 now staged as fp16 (half the write bytes); final fp32 datt written
// once in k_p4.
__global__ __launch_bounds__(256) void k_p3f(const __fp16* __restrict__ att,
                                             const u32* __restrict__ sbuf,
                                             const float* __restrict__ pw,
                                             const float* __restrict__ stats,
                                             __fp16* __restrict__ a3h,
                                             float* __restrict__ statw) {
    __shared__ floatx2 pw2[216];     // [k*36+ch] = (pw[2k][ch], pw[2k+1][ch]), k=c-pair
    __shared__ floatx2 sc2p[18], sh2p[18];
    __shared__ float red2[16][37];
    const int tid = threadIdx.x;
    for (int i = tid; i < 216; i += 256) {
        int k = i / 36, ch = i - k * 36;
        floatx2 t = {pw[(2 * k) * 36 + ch], pw[(2 * k + 1) * 36 + ch]};
        pw2[i] = t;
    }
    if (tid < 18) {
        floatx2 a = {stats[ST_SC2 + 2 * tid], stats[ST_SC2 + 2 * tid + 1]};
        floatx2 bshift = {stats[ST_SH2 + 2 * tid], stats[ST_SH2 + 2 * tid + 1]};
        sc2p[tid] = a;
        sh2p[tid] = bshift;
    }
    __syncthreads();
    const int p = blockIdx.x * 256 + tid;
    const bool act = p < NPIX;
    int b = 0, s = 0;
    if (act) { b = p / NN2; s = p - b * NN2; }
    const floatx2 vzero = {0.f, 0.f};
    const floatx2 vsix  = {6.f, 6.f};
    floatx2 a3p[6] = {vzero, vzero, vzero, vzero, vzero, vzero};
    float a0v[12] = {};
    if (act) {
        const u32* sb = sbuf + (size_t)b * 18 * NN2 + s;
#pragma unroll 3
        for (int pp = 0; pp < 18; ++pp) {
            u32 w = sb[(size_t)pp * NN2];
            floatx2 sv = {unph_lo(w), unph_hi(w)};
            floatx2 u = __builtin_elementwise_fma(sc2p[pp], sv, sh2p[pp]);
            u = __builtin_elementwise_max(u, vzero);
            u = __builtin_elementwise_min(u, vsix);
            floatx2 ux = {u.x, u.x};
            floatx2 uy = {u.y, u.y};
#pragma unroll
            for (int k = 0; k < 6; ++k) {
                a3p[k] = __builtin_elementwise_fma(pw2[k * 36 + 2 * pp], ux, a3p[k]);
                a3p[k] = __builtin_elementwise_fma(pw2[k * 36 + 2 * pp + 1], uy, a3p[k]);
            }
        }
        const __fp16* ab = att + (size_t)b * 12 * NN2 + s;
#pragma unroll
        for (int c = 0; c < 12; ++c) a0v[c] = (float)ab[(size_t)c * NN2];
#pragma unroll
        for (int k = 0; k < 6; ++k) {
            a3h[(size_t)(b * 12 + 2 * k) * NN2 + s]     = (__fp16)a3p[k].x;
            a3h[(size_t)(b * 12 + 2 * k + 1) * NN2 + s] = (__fp16)a3p[k].y;
        }
    }
    const int leader = tid >> 4;
#pragma unroll
    for (int k = 0; k < 6; ++k) {
        float v0 = a3p[k].x, v1 = a3p[k].y;
        float r30 = red16(v0);
        float r31 = red16(v1);
        float rq0 = red16(v0 * v0);
        float rq1 = red16(v1 * v1);
        float rx0 = red16(v0 * a0v[2 * k]);
        float rx1 = red16(v1 * a0v[2 * k + 1]);
        if ((tid & 15) == 0) {
            red2[leader][2 * k]          = r30;
            red2[leader][2 * k + 1]      = r31;
            red2[leader][12 + 2 * k]     = rq0;
            red2[leader][12 + 2 * k + 1] = rq1;
            red2[leader][24 + 2 * k]     = rx0;
            red2[leader][24 + 2 * k + 1] = rx1;
        }
    }
    __syncthreads();
    if (tid < 36) {
        float tot = 0.f;
        for (int l = 0; l < 16; ++l) tot += red2[l][tid];
        int slot = blockIdx.x & 63;
        atomicAdd(&statw[ST_P3 + slot * 36 + tid], tot);
    }
}

// ====== PASS B (fallback, small-ws): full recompute + fused stats =======
__global__ __launch_bounds__(256) void k_p3(const __fp16* __restrict__ att,
                                            const float* __restrict__ wexp,
                                            const float* __restrict__ dww,
                                            const float* __restrict__ pw,
                                            const float* __restrict__ stats,
                                            __fp16* __restrict__ a3h,
                                            float* __restrict__ statw) {
    __shared__ u32  b1p[18][256];
    __shared__ float wexps[432];
    __shared__ float dws[324];
    __shared__ float pws[432];
    __shared__ float sc1s[36], sh1s[36], sc2s[36], sh2s[36];
    __shared__ float red2[32][37];
    const int b = blockIdx.z;
    const int oy0 = blockIdx.y * 14, ox0 = blockIdx.x * 14;
    const int tid = threadIdx.x;
    for (int i = tid; i < 432; i += 256) { wexps[i] = wexp[i]; pws[i] = pw[i]; }
    for (int i = tid; i < 324; i += 256) dws[i] = dww[i];
    if (tid < 36) {
        sc1s[tid] = stats[ST_SC1 + tid]; sh1s[tid] = stats[ST_SH1 + tid];
        sc2s[tid] = stats[ST_SC2 + tid]; sh2s[tid] = stats[ST_SH2 + tid];
    }
    const int lx = tid & 15, ly = tid >> 4;
    const int gy = oy0 - 1 + ly, gx = ox0 - 1 + lx;
    const bool valid = (gy >= 0 && gy < NSEQ && gx >= 0 && gx < NSEQ);
    float a0v[12];
#pragma unroll
    for (int i = 0; i < 12; ++i)
        a0v[i] = valid ? (float)att[(size_t)(b * 12 + i) * NN2 + (size_t)gy * NSEQ + gx] : 0.f;
    __syncthreads();
#pragma unroll 3
    for (int pp = 0; pp < 18; ++pp) {
        float t0 = 0.f, t1 = 0.f;
#pragma unroll
        for (int i = 0; i < 12; ++i) {
            t0 = fmaf(wexps[(2 * pp) * 12 + i], a0v[i], t0);
            t1 = fmaf(wexps[(2 * pp + 1) * 12 + i], a0v[i], t1);
        }
        t0 = fminf(fmaxf(fmaf(sc1s[2 * pp], t0, sh1s[2 * pp]), 0.f), 6.f);
        t1 = fminf(fmaxf(fmaf(sc1s[2 * pp + 1], t1, sh1s[2 * pp + 1]), 0.f), 6.f);
        if (!valid) { t0 = 0.f; t1 = 0.f; }
        b1p[pp][tid] = pack2(t0, t1);
    }
    __syncthreads();
    const bool inter = (ly >= 1 && ly <= 14 && lx >= 1 && lx <= 14 &&
                        gy < NSEQ && gx < NSEQ);
    float a3v[12] = {};
    if (inter) {
        const int base = (ly - 1) * 16 + (lx - 1);
#pragma unroll 3
        for (int pp = 0; pp < 18; ++pp) {
            const u32* bp = &b1p[pp][base];
            float s0 = 0.f, s1 = 0.f;
#pragma unroll
            for (int dy = 0; dy < 3; ++dy)
#pragma unroll
                for (int dx = 0; dx < 3; ++dx) {
                    u32 w = bp[dy * 16 + dx];
                    s0 = fmaf(dws[(2 * pp) * 9 + dy * 3 + dx], unpk_lo(w), s0);
                    s1 = fmaf(dws[(2 * pp + 1) * 9 + dy * 3 + dx], unpk_hi(w), s1);
                }
            float u0 = fminf(fmaxf(fmaf(sc2s[2 * pp], s0, sh2s[2 * pp]), 0.f), 6.f);
            float u1 = fminf(fmaxf(fmaf(sc2s[2 * pp + 1], s1, sh2s[2 * pp + 1]), 0.f), 6.f);
#pragma unroll
            for (int c = 0; c < 12; ++c)
                a3v[c] = fmaf(pws[c * 36 + 2 * pp], u0,
                         fmaf(pws[c * 36 + 2 * pp + 1], u1, a3v[c]));
        }
        const size_t pix = (size_t)gy * NSEQ + gx;
#pragma unroll
        for (int c = 0; c < 12; ++c)
            a3h[(size_t)(b * 12 + c) * NN2 + pix] = (__fp16)a3v[c];
    }
    const int leader = tid >> 3;
#pragma unroll
    for (int c = 0; c < 12; ++c) {
        float r3  = red16(a3v[c]);
        float rq  = red16(a3v[c] * a3v[c]);
        float r30 = red16(a3v[c] * a0v[c]);
        if ((tid & 7) == 0) {
            red2[leader][c]      = r3;
            red2[leader][12 + c] = rq;
            red2[leader][24 + c] = r30;
        }
    }
    __syncthreads();
    if (tid < 36) {
        float tot = 0.f;
        for (int l = 0; l < 32; l += 2) tot += red2[l][tid];
        int slot = (blockIdx.z * 225 + blockIdx.y * 15 + blockIdx.x) & 63;
        atomicAdd(&statw[ST_P3 + slot * 36 + tid], tot);
    }
}

// ============ finalize bn3 + adapt_bn -> affine alpha/beta/gamma =========
__global__ __launch_bounds__(64) void k_fin3(const float* __restrict__ g3,
                                             const float* __restrict__ b3,
                                             const float* __restrict__ ag,
                                             const float* __restrict__ ab,
                                             float* __restrict__ stats) {
    int c = threadIdx.x;
    if (c >= 12) return;
    float S3 = 0.f, S3q = 0.f, S30 = 0.f;
    for (int sl = 0; sl < 64; ++sl) {
        const float* p = stats + ST_P3 + sl * 36;
        S3 += p[c]; S3q += p[12 + c]; S30 += p[24 + c];
    }
    float S0  = stats[ST_MOMSUM + c];
    float S0q = stats[ST_MOMPROD + c * 12 + c];
    const float M = (float)NPIX;
    float m3 = S3 / M, v3 = S3q / M - m3 * m3;
    float pp = g3[c] * rsqrtf(v3 + EPS);
    float qq = b3[c] - m3 * pp;
    float my = (pp * S3 + S0) / M + qq;
    float Syq = pp * pp * S3q + S0q + qq * qq * M + 2.f * pp * S30 + 2.f * pp * qq * S3 + 2.f * qq * S0;
    float vy = Syq / M - my * my;
    float rr = ag[c] * rsqrtf(vy + EPS);
    float ss = ab[c] - my * rr;
    stats[ST_ABG + c] = rr * pp;
    stats[ST_ABG + 12 + c] = rr;
    stats[ST_ABG + 24 + c] = rr * qq + ss;
}

// ====== final attn (affine from fp16 a3/att0 -> fp32 datt, write-only) ===
// + AV via MFMA -> bf16 outm
__global__ __launch_bounds__(256) void k_p4(float* __restrict__ datt,
                                            const __fp16* __restrict__ att0,
                                            const __fp16* __restrict__ a3h,
                                            const float* __restrict__ v,
                                            const float* __restrict__ stats,
                                            bf16* __restrict__ outm) {
    __shared__ bf16 Vtb[32 * 224];    // V^T: [d][x], zero-padded x>=197
    __shared__ bf16 As[16 * 224];     // av rows (bf16), zero-padded
    const int bh = blockIdx.y;
    const int b = bh / 12, hh = bh - b * 12;
    const int y0 = blockIdx.x * 16;
    const int tid = threadIdx.x;
    const size_t vb = (size_t)bh * (NSEQ * HD);
    for (int i = tid; i < 32 * 224; i += 256) {
        int x = i >> 5, d = i & 31;
        float val = (x < NSEQ) ? v[vb + (size_t)x * HD + d] : 0.f;
        Vtb[d * 224 + x] = (bf16)val;
    }
    const float alpha = stats[ST_ABG + hh];
    const float beta  = stats[ST_ABG + 12 + hh];
    const float gamma = stats[ST_ABG + 24 + hh];
    const int tx = tid & 15, ty = tid >> 4;
    const int y = y0 + ty;
    const size_t ab = (size_t)bh * NN2 + (size_t)y * NSEQ;
    As[ty * 224 + 208 + tx] = (bf16)0.f;      // pad cols 208..223
#pragma unroll
    for (int m = 0; m < 13; ++m) {
        int x = tx + m * 16;
        float av = 0.f;
        if (y < NSEQ && x < NSEQ) {
            av = alpha * (float)a3h[ab + x] + beta * (float)att0[ab + x] + gamma;
            datt[ab + x] = av;
        }
        As[ty * 224 + x] = (bf16)av;
    }
    __syncthreads();
    const int lane = tid & 63, wave = tid >> 6;
    if (wave < 2) {
        const int l15 = lane & 15, quad = lane >> 4;
        floatx4 c = {0.f, 0.f, 0.f, 0.f};
#pragma unroll
        for (int ks = 0; ks < 7; ++ks) {
            bf16x8 af  = *(const bf16x8*)&As[l15 * 224 + ks * 32 + quad * 8];
            bf16x8 bfr = *(const bf16x8*)&Vtb[(wave * 16 + l15) * 224 + ks * 32 + quad * 8];
            c = __builtin_amdgcn_mfma_f32_16x16x32_bf16(af, bfr, c, 0, 0, 0);
        }
#pragma unroll
        for (int reg = 0; reg < 4; ++reg) {
            int yy = y0 + quad * 4 + reg;
            if (yy < NSEQ)
                outm[((size_t)b * NSEQ + yy) * DIM + hh * HD + wave * 16 + l15] =
                    (bf16)c[reg];
        }
    }
}

// ========================================================================
extern "C" void kernel_launch(void* const* d_in, const int* in_sizes, int n_in,
                              void* d_out, int out_size, void* d_ws, size_t ws_size,
                              hipStream_t stream) {
    const float* x     = (const float*)d_in[0];
    const float* ln1g  = (const float*)d_in[1];
    const float* ln1b  = (const float*)d_in[2];
    const float* qkvw  = (const float*)d_in[3];
    const float* wexp  = (const float*)d_in[4];
    const float* bn1g  = (const float*)d_in[5];
    const float* bn1b  = (const float*)d_in[6];
    const float* dww   = (const float*)d_in[7];
    const float* bn2g  = (const float*)d_in[8];
    const float* bn2b  = (const float*)d_in[9];
    const float* prow  = (const float*)d_in[10];
    const float* bn3g  = (const float*)d_in[11];
    const float* bn3b  = (const float*)d_in[12];
    const float* abng  = (const float*)d_in[13];
    const float* abnb  = (const float*)d_in[14];
    const float* projw = (const float*)d_in[15];
    const float* projb = (const float*)d_in[16];
    const float* ln2g  = (const float*)d_in[17];
    const float* ln2b  = (const float*)d_in[18];
    const float* fc1w  = (const float*)d_in[19];
    const float* fc1b  = (const float*)d_in[20];
    const float* fc2w  = (const float*)d_in[21];
    const float* fc2b  = (const float*)d_in[22];
    const float* scch  = (const float*)d_in[23];

    if (ws_size < WS_FLOATS * sizeof(float)) return;   // base requirement ~107 MB
    const bool mid = ws_size >= WS_FLOATS_MID * sizeof(float);  // ~196 MB tier

    float* W     = (float*)d_ws;
    bf16*  hb    = (bf16*)(W + O_HB);     // h, then outm, then h2 (sequential)
    bf16*  qbv   = (bf16*)(W + O_Q);      // bf16 q (SQF folded)
    bf16*  kxb   = (bf16*)(W + O_K);      // bf16 k (SQF folded)
    float* v     = W + O_V;
    __fp16* att0 = (__fp16*)(W + O_ATT0); // fp16 softmax output (internal)
    __fp16* a3h  = att0 + (size_t)NH * 32 * NN2;  // fp16 a3 staging (2nd half of slot)
    float* x1    = W + O_X1;
    bf16*  m1    = (bf16*)(W + O_ATT0);   // alias: att0/a3h dead after k_p4
    bf16*  wqkvb = (bf16*)(W + O_WQKV);
    bf16*  wprjb = (bf16*)(W + O_WPRJ);
    bf16*  wfc1b = (bf16*)(W + O_WFC1);
    bf16*  wfc2b = (bf16*)(W + O_WFC2);
    float* stats = W + O_STATS;
    u32*   sbuf  = (u32*)(W + O_SBUF);    // only valid if mid

    float* xout = (float*)d_out;
    float* datt = xout + XSIZE;

    (void)hipMemsetAsync(stats, 0, ST_TOTAL * sizeof(float), stream);
    k_cvt<<<dim3(288, 4), 256, 0, stream>>>(qkvw, projw, fc1w, fc2w,
                                            wqkvb, wprjb, wfc1b, wfc2b);
    k_ln<<<NROWS, 384, 0, stream>>>(x, ln1g, ln1b, hb);
    k_qkv<<<dim3(9, 50), 256, 0, stream>>>(hb, wqkvb, qbv, kxb, v);
    k_score<<<dim3(13, 384), 256, 0, stream>>>(qbv, kxb, att0);
    k_moments<<<512, 256, 0, stream>>>(att0, stats);
    k_fin1<<<1, 64, 0, stream>>>(wexp, bn1g, bn1b, stats);
    if (mid) {
        k_sums2<1><<<dim3(15, 15, 32), 256, 0, stream>>>(att0, wexp, dww, stats, stats, sbuf);
        k_fin2<<<1, 64, 0, stream>>>(bn2g, bn2b, stats);
        k_p3f<<<(NPIX + 255) / 256, 256, 0, stream>>>(att0, sbuf, prow, stats, a3h, stats);
    } else {
        k_sums2<0><<<dim3(15, 15, 32), 256, 0, stream>>>(att0, wexp, dww, stats, stats, nullptr);
        k_fin2<<<1, 64, 0, stream>>>(bn2g, bn2b, stats);
        k_p3<<<dim3(15, 15, 32), 256, 0, stream>>>(att0, wexp, dww, prow, stats, a3h, stats);
    }
    k_fin3<<<1, 64, 0, stream>>>(bn3g, bn3b, abng, abnb, stats);
    k_p4<<<dim3(13, 384), 256, 0, stream>>>(datt, att0, a3h, v, stats, hb);
    k_proj<<<dim3(3, 50), 256, 0, stream>>>(hb, wprjb, projb, x, x1);
    k_ln<<<NROWS, 384, 0, stream>>>(x1, ln2g, ln2b, hb);
    k_fc1<<<dim3(12, 50), 256, 0, stream>>>(hb, wfc1b, fc1b, m1);
    k_fc2<<<dim3(3, 50), 256, 0, stream>>>(m1, wfc2b, fc2b, scch, x1, xout);
}